// Round 14
// baseline (1902.150 us; speedup 1.0000x reference)
//
#include <hip/hip_runtime.h>
#include <cstdint>
#include <cstddef>

// Problem constants
#define L_   8
#define B_   2
#define T_   1024
#define C_   1024
#define H_   16
#define DH_  64
#define DFF_ 4096
#define M_   2048  // B_*T_

typedef __attribute__((ext_vector_type(4))) float f32x4;
typedef __attribute__((ext_vector_type(8))) short short8_t;
typedef __attribute__((ext_vector_type(8))) __bf16 bf16x8_t;
typedef __attribute__((ext_vector_type(4))) unsigned short ushort4_t;
typedef __attribute__((ext_vector_type(8))) unsigned short ushort8_t;

__device__ __forceinline__ float bf2f(unsigned short u) {
  unsigned int i = ((unsigned int)u) << 16;
  return __builtin_bit_cast(float, i);
}
__device__ __forceinline__ unsigned short f2bf(float f) {
  unsigned int u = __builtin_bit_cast(unsigned int, f);
  u += 0x7fff + ((u >> 16) & 1);   // RNE
  return (unsigned short)(u >> 16);
}
__device__ __forceinline__ f32x4 mfma16x16x32(short8_t a, short8_t b, f32x4 c) {
  return __builtin_amdgcn_mfma_f32_16x16x32_bf16(
      __builtin_bit_cast(bf16x8_t, a), __builtin_bit_cast(bf16x8_t, b), c, 0, 0, 0);
}
__device__ __forceinline__ void async_copy16(const void* g, void* l) {
  __builtin_amdgcn_global_load_lds(
      (const __attribute__((address_space(1))) unsigned int*)g,
      (__attribute__((address_space(3))) unsigned int*)l, 16, 0, 0);
}

// ---------------------------------------------------------------------------
// RoPE cos/sin table: tab[t*32 + j] = (cos, sin)(t * theta^{-2j/64}).
// ---------------------------------------------------------------------------
__global__ __launch_bounds__(256) void rope_tab_k(float2* __restrict__ tab) {
  const int idx = blockIdx.x * 256 + threadIdx.x;   // 0..32767
  const int t = idx >> 5, j = idx & 31;
  const float ang = (float)t * exp2f((float)j * -0.41524101186092029f);
  float sn, cs;
  sincosf(ang, &sn, &cs);
  tab[idx] = make_float2(cs, sn);
}

// ---------------------------------------------------------------------------
// Weight conversion, one matrix family per launch:
// W (R x Cc f32) -> W^T (Cc x R bf16) for all 8 layers. 64x64 tiles,
// rotation swizzle (conflict-free both sides, verified r9).
// ---------------------------------------------------------------------------
__global__ __launch_bounds__(256) void convert_one(
    const float* __restrict__ src0, unsigned short* __restrict__ dst0,
    int R, int Cc, int tilesPerLayer) {
  __shared__ float tile[64 * 64];
  const int layer = blockIdx.x / tilesPerLayer;
  const int t = blockIdx.x - layer * tilesPerLayer;
  const float* src = src0 + (size_t)layer * R * Cc;
  unsigned short* dst = dst0 + (size_t)layer * 12582912;
  const int nTc = Cc >> 6;
  const int tr = t / nTc, tc = t - tr * nTc;
  const int r0 = tr * 64, c0 = tc * 64;
  const int tid = threadIdx.x;
  const int tx = tid & 15, ty = tid >> 4;
#pragma unroll
  for (int i = 0; i < 4; ++i) {
    const int row = ty + 16 * i;
    const float4 v = *(const float4*)(src + (size_t)(r0 + row) * Cc + c0 + tx * 4);
    const int uw = (tx + (row >> 3)) & 15;      // rotation swizzle
    *(float4*)&tile[row * 64 + uw * 4] = v;
  }
  __syncthreads();
#pragma unroll
  for (int pass = 0; pass < 2; ++pass) {
    const int chunk = pass * 256 + tid;
    const int c = chunk >> 3;            // out row (source col)
    const int og = chunk & 7;            // off-group; off = og*8
    const int ur = ((c >> 2) + og) & 15; // matching swizzle
    const int col = ur * 4 + (c & 3);
    ushort8_t val;
#pragma unroll
    for (int j = 0; j < 8; ++j) val[j] = f2bf(tile[(og * 8 + j) * 64 + col]);
    *(ushort8_t*)(dst + (size_t)(c0 + c) * R + r0 + og * 8) = val;
  }
}

// ---------------------------------------------------------------------------
// Plain LayerNorm (layer-0 LN1 only)
// ---------------------------------------------------------------------------
__global__ __launch_bounds__(256) void ln_k(const float* __restrict__ X,
                                            const float* __restrict__ gam,
                                            const float* __restrict__ bet,
                                            unsigned short* __restrict__ out) {
  const int row = blockIdx.x;
  const int tid = threadIdx.x;
  const int lane = tid & 63, w = tid >> 6;
  const float4 v = ((const float4*)(X + (size_t)row * C_))[tid];
  float sum = v.x + v.y + v.z + v.w;
  float sq  = v.x*v.x + v.y*v.y + v.z*v.z + v.w*v.w;
#pragma unroll
  for (int d = 1; d < 64; d <<= 1) {
    sum += __shfl_xor(sum, d, 64);
    sq  += __shfl_xor(sq,  d, 64);
  }
  __shared__ float red[8];
  if (lane == 0) { red[w] = sum; red[4 + w] = sq; }
  __syncthreads();
  sum = red[0] + red[1] + red[2] + red[3];
  sq  = red[4] + red[5] + red[6] + red[7];
  const float mean = sum * (1.0f / C_);
  const float var  = sq * (1.0f / C_) - mean * mean;
  const float inv  = rsqrtf(var + 1e-5f);
  const int col = tid * 4;
  const float xs[4] = { v.x, v.y, v.z, v.w };
  ushort4_t ov;
#pragma unroll
  for (int i = 0; i < 4; ++i)
    ov[i] = f2bf((xs[i]-mean)*inv*gam[col+i] + bet[col+i]);
  *(ushort4_t*)(out + (size_t)row * C_ + col) = ov;
}

// ---------------------------------------------------------------------------
// Fused split-K reduce + bias + residual + LayerNorm.
// ---------------------------------------------------------------------------
template<int NS, int FINAL>
__global__ __launch_bounds__(256) void reduce_ln(
    float* __restrict__ h, const float* __restrict__ bias,
    const float* __restrict__ part,
    const float* __restrict__ gam, const float* __restrict__ bet,
    void* __restrict__ out) {
  const int row = blockIdx.x;
  const int tid = threadIdx.x;
  const int lane = tid & 63, w = tid >> 6;
  const size_t base = (size_t)row * C_;
  float4 v = ((const float4*)(h + base))[tid];
  const float4 b = ((const float4*)bias)[tid];
  v.x += b.x; v.y += b.y; v.z += b.z; v.w += b.w;
#pragma unroll
  for (int z = 0; z < NS; ++z) {
    const float4 p = ((const float4*)(part + (size_t)z * M_ * C_ + base))[tid];
    v.x += p.x; v.y += p.y; v.z += p.z; v.w += p.w;
  }
  if (!FINAL) ((float4*)(h + base))[tid] = v;
  float sum = v.x + v.y + v.z + v.w;
  float sq  = v.x*v.x + v.y*v.y + v.z*v.z + v.w*v.w;
#pragma unroll
  for (int d = 1; d < 64; d <<= 1) {
    sum += __shfl_xor(sum, d, 64);
    sq  += __shfl_xor(sq,  d, 64);
  }
  __shared__ float red[8];
  if (lane == 0) { red[w] = sum; red[4 + w] = sq; }
  __syncthreads();
  sum = red[0] + red[1] + red[2] + red[3];
  sq  = red[4] + red[5] + red[6] + red[7];
  const float mean = sum * (1.0f / C_);
  const float var  = sq * (1.0f / C_) - mean * mean;
  const float inv  = rsqrtf(var + 1e-5f);
  const float4 g  = ((const float4*)gam)[tid];
  const float4 be = ((const float4*)bet)[tid];
  if (FINAL) {
    float4 ov;
    ov.x = (v.x-mean)*inv*g.x + be.x;
    ov.y = (v.y-mean)*inv*g.y + be.y;
    ov.z = (v.z-mean)*inv*g.z + be.z;
    ov.w = (v.w-mean)*inv*g.w + be.w;
    ((float4*)out)[(size_t)row * 256 + tid] = ov;
  } else {
    ushort4_t ov;
    const float xs[4] = { v.x, v.y, v.z, v.w };
    const float gs[4] = { g.x, g.y, g.z, g.w };
    const float bs[4] = { be.x, be.y, be.z, be.w };
#pragma unroll
    for (int i = 0; i < 4; ++i)
      ov[i] = f2bf((xs[i]-mean)*inv*gs[i] + bs[i]);
    *(ushort4_t*)((unsigned short*)out + base + tid * 4) = ov;
  }
}

// ---------------------------------------------------------------------------
// GEMM 64x128 tile, BK=32, 4 waves (2x2) of 32x64.
// EPI 0: QKV (N=3072): +bias, RoPE via table; q,k->bf16 (B,T,C); v->(B,H,DH,T)
// ---------------------------------------------------------------------------
__global__ __launch_bounds__(256) void gemm64_qkv(
    const unsigned short* __restrict__ A,
    const unsigned short* __restrict__ Bt,
    const float* __restrict__ bias0,
    const float* __restrict__ bias1,
    const float* __restrict__ bias2,
    const float2* __restrict__ rtab,
    void* __restrict__ out0, void* __restrict__ out1, void* __restrict__ out2,
    int M, int N, int K) {
  __shared__ __align__(16) unsigned short As[64 * 32];
  __shared__ __align__(16) unsigned short Bs[128 * 32];
  const int tid = threadIdx.x;
  const int lane = tid & 63;
  const int w = tid >> 6;
  const int ln15 = lane & 15, lg = lane >> 4;
  const int row0 = blockIdx.y * 64, col0 = blockIdx.x * 128;
  const int wr = w >> 1, wc = w & 1;

  f32x4 acc[2][4] = {};

  const int rA  = tid >> 2,          ccA = (tid & 3) * 8;
  const int rB0 = tid >> 2,          ccB = (tid & 3) * 8;
  const int rB1 = (256 + tid) >> 2;

  for (int kt = 0; kt < K; kt += 32) {
    async_copy16(A  + (size_t)(row0 + rA)  * K + kt + ccA, (char*)As + ((size_t)w * 64) * 16);
    async_copy16(Bt + (size_t)(col0 + rB0) * K + kt + ccB, (char*)Bs + ((size_t)w * 64) * 16);
    async_copy16(Bt + (size_t)(col0 + rB1) * K + kt + ccB, (char*)Bs + ((size_t)(256 + w * 64)) * 16);
    __syncthreads();
    short8_t af[2], bfr[4];
#pragma unroll
    for (int m = 0; m < 2; ++m)
      af[m] = *(const short8_t*)(As + (wr*32 + m*16 + ln15) * 32 + lg * 8);
#pragma unroll
    for (int n = 0; n < 4; ++n)
      bfr[n] = *(const short8_t*)(Bs + (wc*64 + n*16 + ln15) * 32 + lg * 8);
#pragma unroll
    for (int m = 0; m < 2; ++m)
#pragma unroll
      for (int n = 0; n < 4; ++n)
        acc[m][n] = mfma16x16x32(af[m], bfr[n], acc[m][n]);
    __syncthreads();
  }

#pragma unroll
  for (int m = 0; m < 2; ++m) {
#pragma unroll
    for (int n = 0; n < 4; ++n) {
#pragma unroll
      for (int r = 0; r < 4; ++r) {
        const int rg = row0 + wr*32 + m*16 + lg*4 + r;
        const int cg = col0 + wc*64 + n*16 + ln15;
        float v = acc[m][n][r];
        if (cg < 2048) {
          // q or k: +bias, RoPE from table (pair partner = lane^1)
          v += (cg < 1024) ? bias0[cg] : bias1[cg - 1024];
          const float vp = __shfl_xor(v, 1, 64);
          const int j = (cg & 63) >> 1;
          const float2 cs2 = rtab[((rg & 1023) << 5) + j];
          const float ov = (cg & 1) ? (vp * cs2.y + v * cs2.x)
                                    : (v * cs2.x - vp * cs2.y);
          unsigned short* dstp = (cg < 1024) ? (unsigned short*)out0
                                             : (unsigned short*)out1;
          dstp[(size_t)rg * C_ + (cg & 1023)] = f2bf(ov);
        } else {
          const int ch = cg - 2048;
          v += bias2[ch];
          const int hh = ch >> 6, dh = ch & 63;
          const int bb = rg >> 10, t = rg & 1023;
          // Vt layout: (B,H,DH,T)
          ((unsigned short*)out2)[(((size_t)(bb * H_ + hh) * DH_ + dh) << 10) + t] = f2bf(v);
        }
      }
    }
  }
}

// ---------------------------------------------------------------------------
// GEMM 128x128 tile (m97 structure), BK=32, 4 waves of 64x64, optional K-split.
// EPI 2: +bias, exact GELU, write bf16. EPI 3: f32 partial out[z][M][N].
// ---------------------------------------------------------------------------
template<int EPI>
__global__ __launch_bounds__(256) void gemm128(
    const unsigned short* __restrict__ A,
    const unsigned short* __restrict__ Bt,
    const float* __restrict__ bias,
    void* __restrict__ out,
    int M, int N, int K) {
  __shared__ __align__(16) unsigned short As[128 * 32];
  __shared__ __align__(16) unsigned short Bs[128 * 32];
  const int tid = threadIdx.x;
  const int lane = tid & 63;
  const int w = tid >> 6;
  const int ln15 = lane & 15, lg = lane >> 4;
  const int row0 = blockIdx.y * 128, col0 = blockIdx.x * 128;
  const int wr = w >> 1, wc = w & 1;

  const int kper = K / gridDim.z;
  const int k0 = blockIdx.z * kper;

  f32x4 acc[4][4] = {};

  const int r0s = tid >> 2,         cc0 = (tid & 3) * 8;
  const int r1s = (256 + tid) >> 2, cc1 = (tid & 3) * 8;

  for (int kt = k0; kt < k0 + kper; kt += 32) {
    async_copy16(A  + (size_t)(row0 + r0s) * K + kt + cc0, (char*)As + ((size_t)w * 64) * 16);
    async_copy16(A  + (size_t)(row0 + r1s) * K + kt + cc1, (char*)As + ((size_t)(256 + w * 64)) * 16);
    async_copy16(Bt + (size_t)(col0 + r0s) * K + kt + cc0, (char*)Bs + ((size_t)w * 64) * 16);
    async_copy16(Bt + (size_t)(col0 + r1s) * K + kt + cc1, (char*)Bs + ((size_t)(256 + w * 64)) * 16);
    __syncthreads();
    short8_t af[4], bfr[4];
#pragma unroll
    for (int m = 0; m < 4; ++m)
      af[m] = *(const short8_t*)(As + (wr*64 + m*16 + ln15) * 32 + lg * 8);
#pragma unroll
    for (int n = 0; n < 4; ++n)
      bfr[n] = *(const short8_t*)(Bs + (wc*64 + n*16 + ln15) * 32 + lg * 8);
#pragma unroll
    for (int m = 0; m < 4; ++m)
#pragma unroll
      for (int n = 0; n < 4; ++n)
        acc[m][n] = mfma16x16x32(af[m], bfr[n], acc[m][n]);
    __syncthreads();
  }

#pragma unroll
  for (int m = 0; m < 4; ++m) {
#pragma unroll
    for (int n = 0; n < 4; ++n) {
#pragma unroll
      for (int r = 0; r < 4; ++r) {
        const int rg = row0 + wr*64 + m*16 + lg*4 + r;
        const int cg = col0 + wc*64 + n*16 + ln15;
        float v = acc[m][n][r];
        if (EPI == 2) {
          v += bias[cg];
          v = 0.5f * v * (1.0f + erff(v * 0.70710678118654752f));
          ((unsigned short*)out)[(size_t)rg * N + cg] = f2bf(v);
        } else {
          ((float*)out)[((size_t)blockIdx.z * M_ + rg) * (size_t)N + cg] = v;
        }
      }
    }
  }
}

// ---------------------------------------------------------------------------
// Flash attention, wave-independent: grid (T/16, B*H), 64 threads (1 wave).
// KVBLK=128; P LDS [16][136]. VGPR diet: V prefetch split in halves so peak
// pressure < 128 -> __launch_bounds__(64,4) = 4 waves/SIMD.
// ---------------------------------------------------------------------------
#define PSTR 136

template<bool MASK>
__device__ __forceinline__ void attn_tile(
    const int g, const int ln15, const int lg, const int rowg0,
    const unsigned short* __restrict__ Kp,
    const unsigned short* __restrict__ Vp,
    const short8_t aq0, const short8_t aq1,
    float* __restrict__ m_run, float* __restrict__ l_run,
    f32x4* __restrict__ o, unsigned short* __restrict__ P) {
  const unsigned short* kt = Kp + (size_t)g * 128 * C_;
  const unsigned short* vt = Vp + g * 128;
  f32x4 s[8];
#pragma unroll
  for (int n = 0; n < 8; ++n) {
    const short8_t b0 = *(const short8_t*)(kt + (size_t)n * 16 * C_);
    const short8_t b1 = *(const short8_t*)(kt + (size_t)n * 16 * C_ + 32);
    f32x4 z = {};
    z = mfma16x16x32(aq0, b0, z);
    s[n] = mfma16x16x32(aq1, b1, z);
  }
  // first-half V prefetch (c=0,1): overlaps the softmax VALU phase
  short8_t vb0[2][4];
#pragma unroll
  for (int c = 0; c < 2; ++c)
#pragma unroll
    for (int n = 0; n < 4; ++n)
      vb0[c][n] = *(const short8_t*)(vt + (size_t)n * 16 * T_ + c * 32);

  const float SCL = 0.18033688011116012f;   // (1/8) * log2(e)
  float mx[4];
#pragma unroll
  for (int r = 0; r < 4; ++r) {
    float mr = -1e30f;
#pragma unroll
    for (int n = 0; n < 8; ++n) {
      float v = s[n][r] * SCL;
      if (MASK && (g * 128 + n * 16 + ln15) > (rowg0 + r)) v = -1e30f;
      s[n][r] = v;
      mr = fmaxf(mr, v);
    }
    mx[r] = mr;
  }
#pragma unroll
  for (int d = 1; d < 16; d <<= 1)
#pragma unroll
    for (int r = 0; r < 4; ++r) mx[r] = fmaxf(mx[r], __shfl_xor(mx[r], d, 64));
#pragma unroll
  for (int r = 0; r < 4; ++r) {
    const float mn = fmaxf(m_run[r], mx[r]);
    const float scf = exp2f(m_run[r] - mn);
    m_run[r] = mn;
    float rs = 0.0f;
#pragma unroll
    for (int n = 0; n < 8; ++n) {
      const float pv = exp2f(s[n][r] - mn);
      s[n][r] = pv;
      rs += pv;
    }
#pragma unroll
    for (int d = 1; d < 16; d <<= 1) rs += __shfl_xor(rs, d, 64);
    l_run[r] = l_run[r] * scf + rs;
#pragma unroll
    for (int n = 0; n < 4; ++n) o[n][r] *= scf;
  }
  __syncthreads();   // WAR: prior PV reads done
#pragma unroll
  for (int r = 0; r < 4; ++r)
#pragma unroll
    for (int n = 0; n < 8; ++n)
      P[(lg * 4 + r) * PSTR + n * 16 + ln15] = f2bf(s[n][r]);
  __syncthreads();   // RAW
  // second-half V loads (c=2,3): latency hides under the c=0,1 MFMAs
  short8_t vb1[2][4];
#pragma unroll
  for (int c = 0; c < 2; ++c)
#pragma unroll
    for (int n = 0; n < 4; ++n)
      vb1[c][n] = *(const short8_t*)(vt + (size_t)n * 16 * T_ + (c + 2) * 32);
#pragma unroll
  for (int c = 0; c < 2; ++c) {
    const short8_t pa = *(const short8_t*)(P + ln15 * PSTR + c * 32 + lg * 8);
#pragma unroll
    for (int n = 0; n < 4; ++n)
      o[n] = mfma16x16x32(pa, vb0[c][n], o[n]);
  }
#pragma unroll
  for (int c = 0; c < 2; ++c) {
    const short8_t pa = *(const short8_t*)(P + ln15 * PSTR + (c + 2) * 32 + lg * 8);
#pragma unroll
    for (int n = 0; n < 4; ++n)
      o[n] = mfma16x16x32(pa, vb1[c][n], o[n]);
  }
}

__global__ __launch_bounds__(64, 4) void attn_k(const unsigned short* __restrict__ Q,
                                                const unsigned short* __restrict__ Kb,
                                                const unsigned short* __restrict__ Vt,
                                                unsigned short* __restrict__ Y) {
  __shared__ __align__(16) unsigned short P[16 * PSTR];
  const int lane = threadIdx.x;
  const int ln15 = lane & 15, lg = lane >> 4;
  const int qt = blockIdx.x, bh = blockIdx.y;
  const int b = bh >> 4, h = bh & 15;
  const int q0 = qt * 16;

  short8_t aq0, aq1;
  {
    const unsigned short* qp = Q + ((size_t)(b * T_ + q0 + ln15)) * C_ + h * DH_ + lg * 8;
    aq0 = *(const short8_t*)(qp);
    aq1 = *(const short8_t*)(qp + 32);
  }
  float m_run[4] = { -1e30f, -1e30f, -1e30f, -1e30f };
  float l_run[4] = {};
  f32x4 o[4] = {};
  const int rowg0 = q0 + lg * 4;
  const unsigned short* Kp = Kb + ((size_t)b * T_ + ln15) * C_ + h * DH_ + lg * 8;
  const unsigned short* Vp = Vt + ((size_t)bh * DH_ + ln15) * T_ + lg * 8;

  const int kb_last = qt >> 3;
  for (int kb = 0; kb < kb_last; ++kb)
    attn_tile<false>(kb, ln15, lg, rowg0, Kp, Vp, aq0, aq1, m_run, l_run, o, P);
  attn_tile<true>(kb_last, ln15, lg, rowg0, Kp, Vp, aq0, aq1, m_run, l_run, o, P);

#pragma unroll
  for (int n = 0; n < 4; ++n)
#pragma unroll
    for (int r = 0; r < 4; ++r) {
      const float val = o[n][r] / l_run[r];
      Y[((size_t)(b * T_ + rowg0 + r)) * C_ + h * DH_ + n * 16 + ln15] = f2bf(val);
    }
}

// ---------------------------------------------------------------------------
extern "C" void kernel_launch(void* const* d_in, const int* in_sizes, int n_in,
                              void* d_out, int out_size, void* d_ws, size_t ws_size,
                              hipStream_t stream) {
  const float* x    = (const float*)d_in[0];
  const float* Wq   = (const float*)d_in[1];
  const float* bq   = (const float*)d_in[2];
  const float* Wk   = (const float*)d_in[3];
  const float* bk   = (const float*)d_in[4];
  const float* Wv   = (const float*)d_in[5];
  const float* bv   = (const float*)d_in[6];
  const float* Wo   = (const float*)d_in[7];
  const float* bo   = (const float*)d_in[8];
  const float* ln1s = (const float*)d_in[9];
  const float* ln1b = (const float*)d_in[10];
  const float* ln2s = (const float*)d_in[11];
  const float* ln2b = (const float*)d_in[12];
  const float* W1   = (const float*)d_in[13];
  const float* b1   = (const float*)d_in[14];
  const float* W2   = (const float*)d_in[15];
  const float* b2   = (const float*)d_in[16];
  const float* lnfs = (const float*)d_in[17];
  const float* lnfb = (const float*)d_in[18];

  const size_t MB = (size_t)1 << 20;
  char* ws = (char*)d_ws;
  float*          h      = (float*)(ws + 0);              //  8 MB (B,T,C) f32
  unsigned short* a_bf   = (unsigned short*)(ws + 8*MB);  //  4 MB
  unsigned short* q_bf   = (unsigned short*)(ws + 12*MB); //  4 MB
  unsigned short* k_bf   = (unsigned short*)(ws + 16*MB); //  4 MB
  unsigned short* vt_bf  = (unsigned short*)(ws + 20*MB); //  4 MB (B,H,DH,T)
  unsigned short* y_bf   = (unsigned short*)(ws + 24*MB); //  4 MB
  unsigned short* mid_bf = (unsigned short*)(ws + 28*MB); // 16 MB (M,DFF)
  float*          part   = (float*)(ws + 44*MB);          // 32 MB (4 x 8 MB)
  unsigned short* wt_all = (unsigned short*)(ws + 76*MB); // 192 MB
  float2*         rtab   = (float2*)(ws + 268*MB);        // 256 KB

  // upfront: weights -> bf16^T (per-family launches), rope table, LN1(l=0)
  convert_one<<<8 * 256,  256, 0, stream>>>(Wq, wt_all,            1024, 1024, 256);
  convert_one<<<8 * 256,  256, 0, stream>>>(Wk, wt_all + 1048576,  1024, 1024, 256);
  convert_one<<<8 * 256,  256, 0, stream>>>(Wv, wt_all + 2097152,  1024, 1024, 256);
  convert_one<<<8 * 256,  256, 0, stream>>>(Wo, wt_all + 3145728,  1024, 1024, 256);
  convert_one<<<8 * 1024, 256, 0, stream>>>(W1, wt_all + 4194304,  1024, 4096, 1024);
  convert_one<<<8 * 1024, 256, 0, stream>>>(W2, wt_all + 8388608,  4096, 1024, 1024);
  rope_tab_k<<<128, 256, 0, stream>>>(rtab);
  hipMemcpyAsync(h, x, (size_t)M_ * C_ * sizeof(float), hipMemcpyDeviceToDevice, stream);
  ln_k<<<M_, 256, 0, stream>>>(h, ln1s, ln1b, a_bf);

  for (int l = 0; l < L_; ++l) {
    const unsigned short* wt_l = wt_all + (size_t)l * 12582912;
    // fused QKV GEMM + bias + RoPE(table) + V-transpose (64x128 tile, 768 blocks)
    gemm64_qkv<<<dim3(24, 32, 1), 256, 0, stream>>>(a_bf, wt_l,
        bq + l*C_, bk + l*C_, bv + l*C_, rtab, q_bf, k_bf, vt_bf, M_, 3*C_, C_);
    // attention: 2048 wave-independent blocks, KVBLK=128, 4 waves/SIMD
    attn_k<<<dim3(T_/16, B_*H_), 64, 0, stream>>>(q_bf, k_bf, vt_bf, y_bf);
    // output proj: 128^2 tile, split-K=4 -> partials (512 blocks, 2/CU)
    gemm128<3><<<dim3(8, 16, 4), 256, 0, stream>>>(y_bf, wt_l + 3145728,
        nullptr, part, M_, C_, C_);
    // reduce + bo + residual + LN2 -> a_bf
    reduce_ln<4, 0><<<M_, 256, 0, stream>>>(h, bo + l*C_, part,
        ln2s + l*C_, ln2b + l*C_, a_bf);
    // FFN1 + GELU (128^2 tile, 512 blocks)
    gemm128<2><<<dim3(32, 16, 1), 256, 0, stream>>>(a_bf, wt_l + 4194304,
        b1 + l*DFF_, mid_bf, M_, DFF_, C_);
    // FFN2: 128^2 tile, split-K=4 -> partials (512 blocks, 2/CU)
    gemm128<3><<<dim3(8, 16, 4), 256, 0, stream>>>(mid_bf, wt_l + 8388608,
        nullptr, part, M_, C_, DFF_);
    // reduce + b2 + residual + LN(next or final)
    if (l < L_ - 1) {
      reduce_ln<4, 0><<<M_, 256, 0, stream>>>(h, b2 + l*C_, part,
          ln1s + (l+1)*C_, ln1b + (l+1)*C_, a_bf);
    } else {
      reduce_ln<4, 1><<<M_, 256, 0, stream>>>(h, b2 + l*C_, part,
          lnfs, lnfb, d_out);
    }
  }
}

// Round 15
// 1738.107 us; speedup vs baseline: 1.0944x; 1.0944x over previous
//
#include <hip/hip_runtime.h>
#include <cstdint>
#include <cstddef>

// Problem constants
#define L_   8
#define B_   2
#define T_   1024
#define C_   1024
#define H_   16
#define DH_  64
#define DFF_ 4096
#define M_   2048  // B_*T_

typedef __attribute__((ext_vector_type(4))) float f32x4;
typedef __attribute__((ext_vector_type(8))) short short8_t;
typedef __attribute__((ext_vector_type(8))) __bf16 bf16x8_t;
typedef __attribute__((ext_vector_type(4))) unsigned short ushort4_t;
typedef __attribute__((ext_vector_type(8))) unsigned short ushort8_t;

__device__ __forceinline__ float bf2f(unsigned short u) {
  unsigned int i = ((unsigned int)u) << 16;
  return __builtin_bit_cast(float, i);
}
__device__ __forceinline__ unsigned short f2bf(float f) {
  unsigned int u = __builtin_bit_cast(unsigned int, f);
  u += 0x7fff + ((u >> 16) & 1);   // RNE
  return (unsigned short)(u >> 16);
}
__device__ __forceinline__ f32x4 mfma16x16x32(short8_t a, short8_t b, f32x4 c) {
  return __builtin_amdgcn_mfma_f32_16x16x32_bf16(
      __builtin_bit_cast(bf16x8_t, a), __builtin_bit_cast(bf16x8_t, b), c, 0, 0, 0);
}
__device__ __forceinline__ void async_copy16(const void* g, void* l) {
  __builtin_amdgcn_global_load_lds(
      (const __attribute__((address_space(1))) unsigned int*)g,
      (__attribute__((address_space(3))) unsigned int*)l, 16, 0, 0);
}

// ---------------------------------------------------------------------------
// RoPE cos/sin table: tab[t*32 + j] = (cos, sin)(t * theta^{-2j/64}).
// ---------------------------------------------------------------------------
__global__ __launch_bounds__(256) void rope_tab_k(float2* __restrict__ tab) {
  const int idx = blockIdx.x * 256 + threadIdx.x;   // 0..32767
  const int t = idx >> 5, j = idx & 31;
  const float ang = (float)t * exp2f((float)j * -0.41524101186092029f);
  float sn, cs;
  sincosf(ang, &sn, &cs);
  tab[idx] = make_float2(cs, sn);
}

// ---------------------------------------------------------------------------
// Weight conversion, one matrix family per launch:
// W (R x Cc f32) -> W^T (Cc x R bf16) for all 8 layers. 64x64 tiles,
// rotation swizzle (conflict-free both sides, verified r9).
// ---------------------------------------------------------------------------
__global__ __launch_bounds__(256) void convert_one(
    const float* __restrict__ src0, unsigned short* __restrict__ dst0,
    int R, int Cc, int tilesPerLayer) {
  __shared__ float tile[64 * 64];
  const int layer = blockIdx.x / tilesPerLayer;
  const int t = blockIdx.x - layer * tilesPerLayer;
  const float* src = src0 + (size_t)layer * R * Cc;
  unsigned short* dst = dst0 + (size_t)layer * 12582912;
  const int nTc = Cc >> 6;
  const int tr = t / nTc, tc = t - tr * nTc;
  const int r0 = tr * 64, c0 = tc * 64;
  const int tid = threadIdx.x;
  const int tx = tid & 15, ty = tid >> 4;
#pragma unroll
  for (int i = 0; i < 4; ++i) {
    const int row = ty + 16 * i;
    const float4 v = *(const float4*)(src + (size_t)(r0 + row) * Cc + c0 + tx * 4);
    const int uw = (tx + (row >> 3)) & 15;      // rotation swizzle
    *(float4*)&tile[row * 64 + uw * 4] = v;
  }
  __syncthreads();
#pragma unroll
  for (int pass = 0; pass < 2; ++pass) {
    const int chunk = pass * 256 + tid;
    const int c = chunk >> 3;            // out row (source col)
    const int og = chunk & 7;            // off-group; off = og*8
    const int ur = ((c >> 2) + og) & 15; // matching swizzle
    const int col = ur * 4 + (c & 3);
    ushort8_t val;
#pragma unroll
    for (int j = 0; j < 8; ++j) val[j] = f2bf(tile[(og * 8 + j) * 64 + col]);
    *(ushort8_t*)(dst + (size_t)(c0 + c) * R + r0 + og * 8) = val;
  }
}

// ---------------------------------------------------------------------------
// Plain LayerNorm (layer-0 LN1 only)
// ---------------------------------------------------------------------------
__global__ __launch_bounds__(256) void ln_k(const float* __restrict__ X,
                                            const float* __restrict__ gam,
                                            const float* __restrict__ bet,
                                            unsigned short* __restrict__ out) {
  const int row = blockIdx.x;
  const int tid = threadIdx.x;
  const int lane = tid & 63, w = tid >> 6;
  const float4 v = ((const float4*)(X + (size_t)row * C_))[tid];
  float sum = v.x + v.y + v.z + v.w;
  float sq  = v.x*v.x + v.y*v.y + v.z*v.z + v.w*v.w;
#pragma unroll
  for (int d = 1; d < 64; d <<= 1) {
    sum += __shfl_xor(sum, d, 64);
    sq  += __shfl_xor(sq,  d, 64);
  }
  __shared__ float red[8];
  if (lane == 0) { red[w] = sum; red[4 + w] = sq; }
  __syncthreads();
  sum = red[0] + red[1] + red[2] + red[3];
  sq  = red[4] + red[5] + red[6] + red[7];
  const float mean = sum * (1.0f / C_);
  const float var  = sq * (1.0f / C_) - mean * mean;
  const float inv  = rsqrtf(var + 1e-5f);
  const int col = tid * 4;
  const float xs[4] = { v.x, v.y, v.z, v.w };
  ushort4_t ov;
#pragma unroll
  for (int i = 0; i < 4; ++i)
    ov[i] = f2bf((xs[i]-mean)*inv*gam[col+i] + bet[col+i]);
  *(ushort4_t*)(out + (size_t)row * C_ + col) = ov;
}

// ---------------------------------------------------------------------------
// Fused split-K reduce + bias + residual + LayerNorm. Partials are bf16.
// ---------------------------------------------------------------------------
template<int NS, int FINAL>
__global__ __launch_bounds__(256) void reduce_ln(
    float* __restrict__ h, const float* __restrict__ bias,
    const unsigned short* __restrict__ part,
    const float* __restrict__ gam, const float* __restrict__ bet,
    void* __restrict__ out) {
  const int row = blockIdx.x;
  const int tid = threadIdx.x;
  const int lane = tid & 63, w = tid >> 6;
  const size_t base = (size_t)row * C_;
  float4 v = ((const float4*)(h + base))[tid];
  const float4 b = ((const float4*)bias)[tid];
  v.x += b.x; v.y += b.y; v.z += b.z; v.w += b.w;
#pragma unroll
  for (int z = 0; z < NS; ++z) {
    const ushort4_t p = *(const ushort4_t*)(part + (size_t)z * M_ * C_ + base + tid * 4);
    v.x += bf2f(p[0]); v.y += bf2f(p[1]); v.z += bf2f(p[2]); v.w += bf2f(p[3]);
  }
  if (!FINAL) ((float4*)(h + base))[tid] = v;
  float sum = v.x + v.y + v.z + v.w;
  float sq  = v.x*v.x + v.y*v.y + v.z*v.z + v.w*v.w;
#pragma unroll
  for (int d = 1; d < 64; d <<= 1) {
    sum += __shfl_xor(sum, d, 64);
    sq  += __shfl_xor(sq,  d, 64);
  }
  __shared__ float red[8];
  if (lane == 0) { red[w] = sum; red[4 + w] = sq; }
  __syncthreads();
  sum = red[0] + red[1] + red[2] + red[3];
  sq  = red[4] + red[5] + red[6] + red[7];
  const float mean = sum * (1.0f / C_);
  const float var  = sq * (1.0f / C_) - mean * mean;
  const float inv  = rsqrtf(var + 1e-5f);
  const float4 g  = ((const float4*)gam)[tid];
  const float4 be = ((const float4*)bet)[tid];
  if (FINAL) {
    float4 ov;
    ov.x = (v.x-mean)*inv*g.x + be.x;
    ov.y = (v.y-mean)*inv*g.y + be.y;
    ov.z = (v.z-mean)*inv*g.z + be.z;
    ov.w = (v.w-mean)*inv*g.w + be.w;
    ((float4*)out)[(size_t)row * 256 + tid] = ov;
  } else {
    ushort4_t ov;
    const float xs[4] = { v.x, v.y, v.z, v.w };
    const float gs[4] = { g.x, g.y, g.z, g.w };
    const float bs[4] = { be.x, be.y, be.z, be.w };
#pragma unroll
    for (int i = 0; i < 4; ++i)
      ov[i] = f2bf((xs[i]-mean)*inv*gs[i] + bs[i]);
    *(ushort4_t*)((unsigned short*)out + base + tid * 4) = ov;
  }
}

// ---------------------------------------------------------------------------
// GEMM 64x128 tile, BK=32, 4 waves (2x2) of 32x64. blockIdx.z = K-split.
// EPI 0: QKV (N=3072): +bias, RoPE via table; q,k->bf16 (B,T,C); v->(B,H,DH,T)
// EPI 3: write bf16 partial to out0[z][M][N]
// ---------------------------------------------------------------------------
template<int EPI>
__global__ __launch_bounds__(256) void gemm64(
    const unsigned short* __restrict__ A,
    const unsigned short* __restrict__ Bt,
    const float* __restrict__ bias0,
    const float* __restrict__ bias1,
    const float* __restrict__ bias2,
    const float2* __restrict__ rtab,
    void* __restrict__ out0, void* __restrict__ out1, void* __restrict__ out2,
    int M, int N, int K) {
  __shared__ __align__(16) unsigned short As[64 * 32];
  __shared__ __align__(16) unsigned short Bs[128 * 32];
  const int tid = threadIdx.x;
  const int lane = tid & 63;
  const int w = tid >> 6;
  const int ln15 = lane & 15, lg = lane >> 4;
  const int row0 = blockIdx.y * 64, col0 = blockIdx.x * 128;
  const int wr = w >> 1, wc = w & 1;

  const int kper = K / gridDim.z;
  const int k0 = blockIdx.z * kper;

  f32x4 acc[2][4] = {};

  const int rA  = tid >> 2,          ccA = (tid & 3) * 8;
  const int rB0 = tid >> 2,          ccB = (tid & 3) * 8;
  const int rB1 = (256 + tid) >> 2;

  for (int kt = k0; kt < k0 + kper; kt += 32) {
    async_copy16(A  + (size_t)(row0 + rA)  * K + kt + ccA, (char*)As + ((size_t)w * 64) * 16);
    async_copy16(Bt + (size_t)(col0 + rB0) * K + kt + ccB, (char*)Bs + ((size_t)w * 64) * 16);
    async_copy16(Bt + (size_t)(col0 + rB1) * K + kt + ccB, (char*)Bs + ((size_t)(256 + w * 64)) * 16);
    __syncthreads();
    short8_t af[2], bfr[4];
#pragma unroll
    for (int m = 0; m < 2; ++m)
      af[m] = *(const short8_t*)(As + (wr*32 + m*16 + ln15) * 32 + lg * 8);
#pragma unroll
    for (int n = 0; n < 4; ++n)
      bfr[n] = *(const short8_t*)(Bs + (wc*64 + n*16 + ln15) * 32 + lg * 8);
#pragma unroll
    for (int m = 0; m < 2; ++m)
#pragma unroll
      for (int n = 0; n < 4; ++n)
        acc[m][n] = mfma16x16x32(af[m], bfr[n], acc[m][n]);
    __syncthreads();
  }

#pragma unroll
  for (int m = 0; m < 2; ++m) {
#pragma unroll
    for (int n = 0; n < 4; ++n) {
#pragma unroll
      for (int r = 0; r < 4; ++r) {
        const int rg = row0 + wr*32 + m*16 + lg*4 + r;
        const int cg = col0 + wc*64 + n*16 + ln15;
        float v = acc[m][n][r];
        if (EPI == 0) {
          if (cg < 2048) {
            // q or k: +bias, RoPE from table (pair partner = lane^1)
            v += (cg < 1024) ? bias0[cg] : bias1[cg - 1024];
            const float vp = __shfl_xor(v, 1, 64);
            const int j = (cg & 63) >> 1;
            const float2 cs2 = rtab[((rg & 1023) << 5) + j];
            const float ov = (cg & 1) ? (vp * cs2.y + v * cs2.x)
                                      : (v * cs2.x - vp * cs2.y);
            unsigned short* dstp = (cg < 1024) ? (unsigned short*)out0
                                               : (unsigned short*)out1;
            dstp[(size_t)rg * C_ + (cg & 1023)] = f2bf(ov);
          } else {
            const int ch = cg - 2048;
            v += bias2[ch];
            const int hh = ch >> 6, dh = ch & 63;
            const int bb = rg >> 10, t = rg & 1023;
            // Vt layout: (B,H,DH,T)
            ((unsigned short*)out2)[(((size_t)(bb * H_ + hh) * DH_ + dh) << 10) + t] = f2bf(v);
          }
        } else {
          ((unsigned short*)out0)[((size_t)blockIdx.z * M_ + rg) * (size_t)N + cg] = f2bf(v);
        }
      }
    }
  }
}

// ---------------------------------------------------------------------------
// GEMM 128x128 tile (m97 structure), BK=32, 4 waves of 64x64, optional K-split.
// EPI 2: +bias, exact GELU, write bf16. EPI 3: bf16 partial out[z][M][N].
// ---------------------------------------------------------------------------
template<int EPI>
__global__ __launch_bounds__(256) void gemm128(
    const unsigned short* __restrict__ A,
    const unsigned short* __restrict__ Bt,
    const float* __restrict__ bias,
    void* __restrict__ out,
    int M, int N, int K) {
  __shared__ __align__(16) unsigned short As[128 * 32];
  __shared__ __align__(16) unsigned short Bs[128 * 32];
  const int tid = threadIdx.x;
  const int lane = tid & 63;
  const int w = tid >> 6;
  const int ln15 = lane & 15, lg = lane >> 4;
  const int row0 = blockIdx.y * 128, col0 = blockIdx.x * 128;
  const int wr = w >> 1, wc = w & 1;

  const int kper = K / gridDim.z;
  const int k0 = blockIdx.z * kper;

  f32x4 acc[4][4] = {};

  const int r0s = tid >> 2,         cc0 = (tid & 3) * 8;
  const int r1s = (256 + tid) >> 2, cc1 = (tid & 3) * 8;

  for (int kt = k0; kt < k0 + kper; kt += 32) {
    async_copy16(A  + (size_t)(row0 + r0s) * K + kt + cc0, (char*)As + ((size_t)w * 64) * 16);
    async_copy16(A  + (size_t)(row0 + r1s) * K + kt + cc1, (char*)As + ((size_t)(256 + w * 64)) * 16);
    async_copy16(Bt + (size_t)(col0 + r0s) * K + kt + cc0, (char*)Bs + ((size_t)w * 64) * 16);
    async_copy16(Bt + (size_t)(col0 + r1s) * K + kt + cc1, (char*)Bs + ((size_t)(256 + w * 64)) * 16);
    __syncthreads();
    short8_t af[4], bfr[4];
#pragma unroll
    for (int m = 0; m < 4; ++m)
      af[m] = *(const short8_t*)(As + (wr*64 + m*16 + ln15) * 32 + lg * 8);
#pragma unroll
    for (int n = 0; n < 4; ++n)
      bfr[n] = *(const short8_t*)(Bs + (wc*64 + n*16 + ln15) * 32 + lg * 8);
#pragma unroll
    for (int m = 0; m < 4; ++m)
#pragma unroll
      for (int n = 0; n < 4; ++n)
        acc[m][n] = mfma16x16x32(af[m], bfr[n], acc[m][n]);
    __syncthreads();
  }

#pragma unroll
  for (int m = 0; m < 4; ++m) {
#pragma unroll
    for (int n = 0; n < 4; ++n) {
#pragma unroll
      for (int r = 0; r < 4; ++r) {
        const int rg = row0 + wr*64 + m*16 + lg*4 + r;
        const int cg = col0 + wc*64 + n*16 + ln15;
        float v = acc[m][n][r];
        if (EPI == 2) {
          v += bias[cg];
          v = 0.5f * v * (1.0f + erff(v * 0.70710678118654752f));
          ((unsigned short*)out)[(size_t)rg * N + cg] = f2bf(v);
        } else {
          ((unsigned short*)out)[((size_t)blockIdx.z * M_ + rg) * (size_t)N + cg] = f2bf(v);
        }
      }
    }
  }
}

// ---------------------------------------------------------------------------
// Flash attention, wave-independent (r13 form): grid (T/16, B*H), 64 threads.
// KVBLK=128; P LDS [16][136] (no 16-way conflict on pa ds_read_b128).
// ---------------------------------------------------------------------------
#define PSTR 136

template<bool MASK>
__device__ __forceinline__ void attn_tile(
    const int g, const int ln15, const int lg, const int rowg0,
    const unsigned short* __restrict__ Kp,
    const unsigned short* __restrict__ Vp,
    const short8_t aq0, const short8_t aq1,
    float* __restrict__ m_run, float* __restrict__ l_run,
    f32x4* __restrict__ o, unsigned short* __restrict__ P) {
  const unsigned short* kt = Kp + (size_t)g * 128 * C_;
  const unsigned short* vt = Vp + g * 128;
  f32x4 s[8];
#pragma unroll
  for (int n = 0; n < 8; ++n) {
    const short8_t b0 = *(const short8_t*)(kt + (size_t)n * 16 * C_);
    const short8_t b1 = *(const short8_t*)(kt + (size_t)n * 16 * C_ + 32);
    f32x4 z = {};
    z = mfma16x16x32(aq0, b0, z);
    s[n] = mfma16x16x32(aq1, b1, z);
  }
  // prefetch V fragments; loads overlap the softmax VALU phase
  short8_t vb[4][4];
#pragma unroll
  for (int c = 0; c < 4; ++c)
#pragma unroll
    for (int n = 0; n < 4; ++n)
      vb[c][n] = *(const short8_t*)(vt + (size_t)n * 16 * T_ + c * 32);

  const float SCL = 0.18033688011116012f;   // (1/8) * log2(e)
  float mx[4];
#pragma unroll
  for (int r = 0; r < 4; ++r) {
    float mr = -1e30f;
#pragma unroll
    for (int n = 0; n < 8; ++n) {
      float v = s[n][r] * SCL;
      if (MASK && (g * 128 + n * 16 + ln15) > (rowg0 + r)) v = -1e30f;
      s[n][r] = v;
      mr = fmaxf(mr, v);
    }
    mx[r] = mr;
  }
#pragma unroll
  for (int d = 1; d < 16; d <<= 1)
#pragma unroll
    for (int r = 0; r < 4; ++r) mx[r] = fmaxf(mx[r], __shfl_xor(mx[r], d, 64));
#pragma unroll
  for (int r = 0; r < 4; ++r) {
    const float mn = fmaxf(m_run[r], mx[r]);
    const float scf = exp2f(m_run[r] - mn);
    m_run[r] = mn;
    float rs = 0.0f;
#pragma unroll
    for (int n = 0; n < 8; ++n) {
      const float pv = exp2f(s[n][r] - mn);
      s[n][r] = pv;
      rs += pv;
    }
#pragma unroll
    for (int d = 1; d < 16; d <<= 1) rs += __shfl_xor(rs, d, 64);
    l_run[r] = l_run[r] * scf + rs;
#pragma unroll
    for (int n = 0; n < 4; ++n) o[n][r] *= scf;
  }
  __syncthreads();   // WAR: prior PV reads done
#pragma unroll
  for (int r = 0; r < 4; ++r)
#pragma unroll
    for (int n = 0; n < 8; ++n)
      P[(lg * 4 + r) * PSTR + n * 16 + ln15] = f2bf(s[n][r]);
  __syncthreads();   // RAW
#pragma unroll
  for (int c = 0; c < 4; ++c) {
    const short8_t pa = *(const short8_t*)(P + ln15 * PSTR + c * 32 + lg * 8);
#pragma unroll
    for (int n = 0; n < 4; ++n)
      o[n] = mfma16x16x32(pa, vb[c][n], o[n]);
  }
}

__global__ __launch_bounds__(64) void attn_k(const unsigned short* __restrict__ Q,
                                             const unsigned short* __restrict__ Kb,
                                             const unsigned short* __restrict__ Vt,
                                             unsigned short* __restrict__ Y) {
  __shared__ __align__(16) unsigned short P[16 * PSTR];
  const int lane = threadIdx.x;
  const int ln15 = lane & 15, lg = lane >> 4;
  const int qt = blockIdx.x, bh = blockIdx.y;
  const int b = bh >> 4, h = bh & 15;
  const int q0 = qt * 16;

  short8_t aq0, aq1;
  {
    const unsigned short* qp = Q + ((size_t)(b * T_ + q0 + ln15)) * C_ + h * DH_ + lg * 8;
    aq0 = *(const short8_t*)(qp);
    aq1 = *(const short8_t*)(qp + 32);
  }
  float m_run[4] = { -1e30f, -1e30f, -1e30f, -1e30f };
  float l_run[4] = {};
  f32x4 o[4] = {};
  const int rowg0 = q0 + lg * 4;
  const unsigned short* Kp = Kb + ((size_t)b * T_ + ln15) * C_ + h * DH_ + lg * 8;
  const unsigned short* Vp = Vt + ((size_t)bh * DH_ + ln15) * T_ + lg * 8;

  const int kb_last = qt >> 3;
  for (int kb = 0; kb < kb_last; ++kb)
    attn_tile<false>(kb, ln15, lg, rowg0, Kp, Vp, aq0, aq1, m_run, l_run, o, P);
  attn_tile<true>(kb_last, ln15, lg, rowg0, Kp, Vp, aq0, aq1, m_run, l_run, o, P);

#pragma unroll
  for (int n = 0; n < 4; ++n)
#pragma unroll
    for (int r = 0; r < 4; ++r) {
      const float val = o[n][r] / l_run[r];
      Y[((size_t)(b * T_ + rowg0 + r)) * C_ + h * DH_ + n * 16 + ln15] = f2bf(val);
    }
}

// ---------------------------------------------------------------------------
extern "C" void kernel_launch(void* const* d_in, const int* in_sizes, int n_in,
                              void* d_out, int out_size, void* d_ws, size_t ws_size,
                              hipStream_t stream) {
  const float* x    = (const float*)d_in[0];
  const float* Wq   = (const float*)d_in[1];
  const float* bq   = (const float*)d_in[2];
  const float* Wk   = (const float*)d_in[3];
  const float* bk   = (const float*)d_in[4];
  const float* Wv   = (const float*)d_in[5];
  const float* bv   = (const float*)d_in[6];
  const float* Wo   = (const float*)d_in[7];
  const float* bo   = (const float*)d_in[8];
  const float* ln1s = (const float*)d_in[9];
  const float* ln1b = (const float*)d_in[10];
  const float* ln2s = (const float*)d_in[11];
  const float* ln2b = (const float*)d_in[12];
  const float* W1   = (const float*)d_in[13];
  const float* b1   = (const float*)d_in[14];
  const float* W2   = (const float*)d_in[15];
  const float* b2   = (const float*)d_in[16];
  const float* lnfs = (const float*)d_in[17];
  const float* lnfb = (const float*)d_in[18];

  const size_t MB = (size_t)1 << 20;
  char* ws = (char*)d_ws;
  float*          h      = (float*)(ws + 0);              //  8 MB (B,T,C) f32
  unsigned short* a_bf   = (unsigned short*)(ws + 8*MB);  //  4 MB
  unsigned short* q_bf   = (unsigned short*)(ws + 12*MB); //  4 MB
  unsigned short* k_bf   = (unsigned short*)(ws + 16*MB); //  4 MB
  unsigned short* vt_bf  = (unsigned short*)(ws + 20*MB); //  4 MB (B,H,DH,T)
  unsigned short* y_bf   = (unsigned short*)(ws + 24*MB); //  4 MB
  unsigned short* mid_bf = (unsigned short*)(ws + 28*MB); // 16 MB (M,DFF)
  unsigned short* part   = (unsigned short*)(ws + 44*MB); // 16 MB (4 x 4 MB bf16)
  unsigned short* wt_all = (unsigned short*)(ws + 76*MB); // 192 MB
  float2*         rtab   = (float2*)(ws + 268*MB);        // 256 KB

  // upfront: weights -> bf16^T (per-family launches), rope table, LN1(l=0)
  convert_one<<<8 * 256,  256, 0, stream>>>(Wq, wt_all,            1024, 1024, 256);
  convert_one<<<8 * 256,  256, 0, stream>>>(Wk, wt_all + 1048576,  1024, 1024, 256);
  convert_one<<<8 * 256,  256, 0, stream>>>(Wv, wt_all + 2097152,  1024, 1024, 256);
  convert_one<<<8 * 256,  256, 0, stream>>>(Wo, wt_all + 3145728,  1024, 1024, 256);
  convert_one<<<8 * 1024, 256, 0, stream>>>(W1, wt_all + 4194304,  1024, 4096, 1024);
  convert_one<<<8 * 1024, 256, 0, stream>>>(W2, wt_all + 8388608,  4096, 1024, 1024);
  rope_tab_k<<<128, 256, 0, stream>>>(rtab);
  hipMemcpyAsync(h, x, (size_t)M_ * C_ * sizeof(float), hipMemcpyDeviceToDevice, stream);
  ln_k<<<M_, 256, 0, stream>>>(h, ln1s, ln1b, a_bf);

  for (int l = 0; l < L_; ++l) {
    const unsigned short* wt_l = wt_all + (size_t)l * 12582912;
    // fused QKV GEMM + bias + RoPE(table) + V-transpose (64x128 tile, 768 blocks)
    gemm64<0><<<dim3(24, 32, 1), 256, 0, stream>>>(a_bf, wt_l,
        bq + l*C_, bk + l*C_, bv + l*C_, rtab, q_bf, k_bf, vt_bf, M_, 3*C_, C_);
    // attention: 2048 wave-independent blocks, KVBLK=128
    attn_k<<<dim3(T_/16, B_*H_), 64, 0, stream>>>(q_bf, k_bf, vt_bf, y_bf);
    // output proj, split-K=2 -> bf16 partials (512 blocks)
    gemm64<3><<<dim3(8, 32, 2), 256, 0, stream>>>(y_bf, wt_l + 3145728,
        nullptr, nullptr, nullptr, nullptr, part, nullptr, nullptr, M_, C_, C_);
    // reduce + bo + residual + LN2 -> a_bf
    reduce_ln<2, 0><<<M_, 256, 0, stream>>>(h, bo + l*C_, part,
        ln2s + l*C_, ln2b + l*C_, a_bf);
    // FFN1 + GELU (128^2 tile, 512 blocks)
    gemm128<2><<<dim3(32, 16, 1), 256, 0, stream>>>(a_bf, wt_l + 4194304,
        b1 + l*DFF_, mid_bf, M_, DFF_, C_);
    // FFN2: 128^2 tile, split-K=4 -> bf16 partials (512 blocks, 2/CU)
    gemm128<3><<<dim3(8, 16, 4), 256, 0, stream>>>(mid_bf, wt_l + 8388608,
        nullptr, part, M_, C_, DFF_);
    // reduce + b2 + residual + LN(next or final)
    if (l < L_ - 1) {
      reduce_ln<4, 0><<<M_, 256, 0, stream>>>(h, b2 + l*C_, part,
          ln1s + (l+1)*C_, ln1b + (l+1)*C_, a_bf);
    } else {
      reduce_ln<4, 1><<<M_, 256, 0, stream>>>(h, b2 + l*C_, part,
          lnfs, lnfb, d_out);
    }
  }
}

// Round 16
// 1655.165 us; speedup vs baseline: 1.1492x; 1.0501x over previous
//
#include <hip/hip_runtime.h>
#include <cstdint>
#include <cstddef>

// Problem constants
#define L_   8
#define B_   2
#define T_   1024
#define C_   1024
#define H_   16
#define DH_  64
#define DFF_ 4096
#define M_   2048  // B_*T_

typedef __attribute__((ext_vector_type(4))) float f32x4;
typedef __attribute__((ext_vector_type(8))) short short8_t;
typedef __attribute__((ext_vector_type(8))) __bf16 bf16x8_t;
typedef __attribute__((ext_vector_type(4))) unsigned short ushort4_t;
typedef __attribute__((ext_vector_type(8))) unsigned short ushort8_t;

__device__ __forceinline__ float bf2f(unsigned short u) {
  unsigned int i = ((unsigned int)u) << 16;
  return __builtin_bit_cast(float, i);
}
__device__ __forceinline__ unsigned short f2bf(float f) {
  unsigned int u = __builtin_bit_cast(unsigned int, f);
  u += 0x7fff + ((u >> 16) & 1);   // RNE
  return (unsigned short)(u >> 16);
}
__device__ __forceinline__ f32x4 mfma16x16x32(short8_t a, short8_t b, f32x4 c) {
  return __builtin_amdgcn_mfma_f32_16x16x32_bf16(
      __builtin_bit_cast(bf16x8_t, a), __builtin_bit_cast(bf16x8_t, b), c, 0, 0, 0);
}
__device__ __forceinline__ void async_copy16(const void* g, void* l) {
  __builtin_amdgcn_global_load_lds(
      (const __attribute__((address_space(1))) unsigned int*)g,
      (__attribute__((address_space(3))) unsigned int*)l, 16, 0, 0);
}

// ---------------------------------------------------------------------------
// RoPE cos/sin table: tab[t*32 + j] = (cos, sin)(t * theta^{-2j/64}).
// ---------------------------------------------------------------------------
__global__ __launch_bounds__(256) void rope_tab_k(float2* __restrict__ tab) {
  const int idx = blockIdx.x * 256 + threadIdx.x;   // 0..32767
  const int t = idx >> 5, j = idx & 31;
  const float ang = (float)t * exp2f((float)j * -0.41524101186092029f);
  float sn, cs;
  sincosf(ang, &sn, &cs);
  tab[idx] = make_float2(cs, sn);
}

// ---------------------------------------------------------------------------
// Weight conversion, one matrix family per launch:
// W (R x Cc f32) -> W^T (Cc x R bf16) for all 8 layers. 64x64 tiles,
// rotation swizzle (conflict-free both sides, verified r9).
// ---------------------------------------------------------------------------
__global__ __launch_bounds__(256) void convert_one(
    const float* __restrict__ src0, unsigned short* __restrict__ dst0,
    int R, int Cc, int tilesPerLayer) {
  __shared__ float tile[64 * 64];
  const int layer = blockIdx.x / tilesPerLayer;
  const int t = blockIdx.x - layer * tilesPerLayer;
  const float* src = src0 + (size_t)layer * R * Cc;
  unsigned short* dst = dst0 + (size_t)layer * 12582912;
  const int nTc = Cc >> 6;
  const int tr = t / nTc, tc = t - tr * nTc;
  const int r0 = tr * 64, c0 = tc * 64;
  const int tid = threadIdx.x;
  const int tx = tid & 15, ty = tid >> 4;
#pragma unroll
  for (int i = 0; i < 4; ++i) {
    const int row = ty + 16 * i;
    const float4 v = *(const float4*)(src + (size_t)(r0 + row) * Cc + c0 + tx * 4);
    const int uw = (tx + (row >> 3)) & 15;      // rotation swizzle
    *(float4*)&tile[row * 64 + uw * 4] = v;
  }
  __syncthreads();
#pragma unroll
  for (int pass = 0; pass < 2; ++pass) {
    const int chunk = pass * 256 + tid;
    const int c = chunk >> 3;            // out row (source col)
    const int og = chunk & 7;            // off-group; off = og*8
    const int ur = ((c >> 2) + og) & 15; // matching swizzle
    const int col = ur * 4 + (c & 3);
    ushort8_t val;
#pragma unroll
    for (int j = 0; j < 8; ++j) val[j] = f2bf(tile[(og * 8 + j) * 64 + col]);
    *(ushort8_t*)(dst + (size_t)(c0 + c) * R + r0 + og * 8) = val;
  }
}

// ---------------------------------------------------------------------------
// Plain LayerNorm (layer-0 LN1 only)
// ---------------------------------------------------------------------------
__global__ __launch_bounds__(256) void ln_k(const float* __restrict__ X,
                                            const float* __restrict__ gam,
                                            const float* __restrict__ bet,
                                            unsigned short* __restrict__ out) {
  const int row = blockIdx.x;
  const int tid = threadIdx.x;
  const int lane = tid & 63, w = tid >> 6;
  const float4 v = ((const float4*)(X + (size_t)row * C_))[tid];
  float sum = v.x + v.y + v.z + v.w;
  float sq  = v.x*v.x + v.y*v.y + v.z*v.z + v.w*v.w;
#pragma unroll
  for (int d = 1; d < 64; d <<= 1) {
    sum += __shfl_xor(sum, d, 64);
    sq  += __shfl_xor(sq,  d, 64);
  }
  __shared__ float red[8];
  if (lane == 0) { red[w] = sum; red[4 + w] = sq; }
  __syncthreads();
  sum = red[0] + red[1] + red[2] + red[3];
  sq  = red[4] + red[5] + red[6] + red[7];
  const float mean = sum * (1.0f / C_);
  const float var  = sq * (1.0f / C_) - mean * mean;
  const float inv  = rsqrtf(var + 1e-5f);
  const int col = tid * 4;
  const float xs[4] = { v.x, v.y, v.z, v.w };
  ushort4_t ov;
#pragma unroll
  for (int i = 0; i < 4; ++i)
    ov[i] = f2bf((xs[i]-mean)*inv*gam[col+i] + bet[col+i]);
  *(ushort4_t*)(out + (size_t)row * C_ + col) = ov;
}

// ---------------------------------------------------------------------------
// Fused split-K reduce + bias + residual + LayerNorm. Partials are bf16.
// ---------------------------------------------------------------------------
template<int NS, int FINAL>
__global__ __launch_bounds__(256) void reduce_ln(
    float* __restrict__ h, const float* __restrict__ bias,
    const unsigned short* __restrict__ part,
    const float* __restrict__ gam, const float* __restrict__ bet,
    void* __restrict__ out) {
  const int row = blockIdx.x;
  const int tid = threadIdx.x;
  const int lane = tid & 63, w = tid >> 6;
  const size_t base = (size_t)row * C_;
  float4 v = ((const float4*)(h + base))[tid];
  const float4 b = ((const float4*)bias)[tid];
  v.x += b.x; v.y += b.y; v.z += b.z; v.w += b.w;
#pragma unroll
  for (int z = 0; z < NS; ++z) {
    const ushort4_t p = *(const ushort4_t*)(part + (size_t)z * M_ * C_ + base + tid * 4);
    v.x += bf2f(p[0]); v.y += bf2f(p[1]); v.z += bf2f(p[2]); v.w += bf2f(p[3]);
  }
  if (!FINAL) ((float4*)(h + base))[tid] = v;
  float sum = v.x + v.y + v.z + v.w;
  float sq  = v.x*v.x + v.y*v.y + v.z*v.z + v.w*v.w;
#pragma unroll
  for (int d = 1; d < 64; d <<= 1) {
    sum += __shfl_xor(sum, d, 64);
    sq  += __shfl_xor(sq,  d, 64);
  }
  __shared__ float red[8];
  if (lane == 0) { red[w] = sum; red[4 + w] = sq; }
  __syncthreads();
  sum = red[0] + red[1] + red[2] + red[3];
  sq  = red[4] + red[5] + red[6] + red[7];
  const float mean = sum * (1.0f / C_);
  const float var  = sq * (1.0f / C_) - mean * mean;
  const float inv  = rsqrtf(var + 1e-5f);
  const float4 g  = ((const float4*)gam)[tid];
  const float4 be = ((const float4*)bet)[tid];
  if (FINAL) {
    float4 ov;
    ov.x = (v.x-mean)*inv*g.x + be.x;
    ov.y = (v.y-mean)*inv*g.y + be.y;
    ov.z = (v.z-mean)*inv*g.z + be.z;
    ov.w = (v.w-mean)*inv*g.w + be.w;
    ((float4*)out)[(size_t)row * 256 + tid] = ov;
  } else {
    ushort4_t ov;
    const float xs[4] = { v.x, v.y, v.z, v.w };
    const float gs[4] = { g.x, g.y, g.z, g.w };
    const float bs[4] = { be.x, be.y, be.z, be.w };
#pragma unroll
    for (int i = 0; i < 4; ++i)
      ov[i] = f2bf((xs[i]-mean)*inv*gs[i] + bs[i]);
    *(ushort4_t*)((unsigned short*)out + base + tid * 4) = ov;
  }
}

// ---------------------------------------------------------------------------
// GEMM 64x128 tile, BK=32, 4 waves (2x2) of 32x64. blockIdx.z = K-split.
// EPI 0: QKV (N=3072): +bias, RoPE via table; q,k->bf16 (B,T,C); v->(B,H,DH,T)
// EPI 3: write bf16 partial to out0[z][M][N]
// ---------------------------------------------------------------------------
template<int EPI>
__global__ __launch_bounds__(256) void gemm64(
    const unsigned short* __restrict__ A,
    const unsigned short* __restrict__ Bt,
    const float* __restrict__ bias0,
    const float* __restrict__ bias1,
    const float* __restrict__ bias2,
    const float2* __restrict__ rtab,
    void* __restrict__ out0, void* __restrict__ out1, void* __restrict__ out2,
    int M, int N, int K) {
  __shared__ __align__(16) unsigned short As[64 * 32];
  __shared__ __align__(16) unsigned short Bs[128 * 32];
  const int tid = threadIdx.x;
  const int lane = tid & 63;
  const int w = tid >> 6;
  const int ln15 = lane & 15, lg = lane >> 4;
  const int row0 = blockIdx.y * 64, col0 = blockIdx.x * 128;
  const int wr = w >> 1, wc = w & 1;

  const int kper = K / gridDim.z;
  const int k0 = blockIdx.z * kper;

  f32x4 acc[2][4] = {};

  const int rA  = tid >> 2,          ccA = (tid & 3) * 8;
  const int rB0 = tid >> 2,          ccB = (tid & 3) * 8;
  const int rB1 = (256 + tid) >> 2;

  for (int kt = k0; kt < k0 + kper; kt += 32) {
    async_copy16(A  + (size_t)(row0 + rA)  * K + kt + ccA, (char*)As + ((size_t)w * 64) * 16);
    async_copy16(Bt + (size_t)(col0 + rB0) * K + kt + ccB, (char*)Bs + ((size_t)w * 64) * 16);
    async_copy16(Bt + (size_t)(col0 + rB1) * K + kt + ccB, (char*)Bs + ((size_t)(256 + w * 64)) * 16);
    __syncthreads();
    short8_t af[2], bfr[4];
#pragma unroll
    for (int m = 0; m < 2; ++m)
      af[m] = *(const short8_t*)(As + (wr*32 + m*16 + ln15) * 32 + lg * 8);
#pragma unroll
    for (int n = 0; n < 4; ++n)
      bfr[n] = *(const short8_t*)(Bs + (wc*64 + n*16 + ln15) * 32 + lg * 8);
#pragma unroll
    for (int m = 0; m < 2; ++m)
#pragma unroll
      for (int n = 0; n < 4; ++n)
        acc[m][n] = mfma16x16x32(af[m], bfr[n], acc[m][n]);
    __syncthreads();
  }

#pragma unroll
  for (int m = 0; m < 2; ++m) {
#pragma unroll
    for (int n = 0; n < 4; ++n) {
#pragma unroll
      for (int r = 0; r < 4; ++r) {
        const int rg = row0 + wr*32 + m*16 + lg*4 + r;
        const int cg = col0 + wc*64 + n*16 + ln15;
        float v = acc[m][n][r];
        if (EPI == 0) {
          if (cg < 2048) {
            // q or k: +bias, RoPE from table (pair partner = lane^1)
            v += (cg < 1024) ? bias0[cg] : bias1[cg - 1024];
            const float vp = __shfl_xor(v, 1, 64);
            const int j = (cg & 63) >> 1;
            const float2 cs2 = rtab[((rg & 1023) << 5) + j];
            const float ov = (cg & 1) ? (vp * cs2.y + v * cs2.x)
                                      : (v * cs2.x - vp * cs2.y);
            unsigned short* dstp = (cg < 1024) ? (unsigned short*)out0
                                               : (unsigned short*)out1;
            dstp[(size_t)rg * C_ + (cg & 1023)] = f2bf(ov);
          } else {
            const int ch = cg - 2048;
            v += bias2[ch];
            const int hh = ch >> 6, dh = ch & 63;
            const int bb = rg >> 10, t = rg & 1023;
            // Vt layout: (B,H,DH,T)
            ((unsigned short*)out2)[(((size_t)(bb * H_ + hh) * DH_ + dh) << 10) + t] = f2bf(v);
          }
        } else {
          ((unsigned short*)out0)[((size_t)blockIdx.z * M_ + rg) * (size_t)N + cg] = f2bf(v);
        }
      }
    }
  }
}

// ---------------------------------------------------------------------------
// GEMM 128x128 tile (m97 structure), BK=32, 4 waves of 64x64, optional K-split.
// EPI 2: +bias, exact GELU, write bf16. EPI 3: bf16 partial out[z][M][N].
// ---------------------------------------------------------------------------
template<int EPI>
__global__ __launch_bounds__(256) void gemm128(
    const unsigned short* __restrict__ A,
    const unsigned short* __restrict__ Bt,
    const float* __restrict__ bias,
    void* __restrict__ out,
    int M, int N, int K) {
  __shared__ __align__(16) unsigned short As[128 * 32];
  __shared__ __align__(16) unsigned short Bs[128 * 32];
  const int tid = threadIdx.x;
  const int lane = tid & 63;
  const int w = tid >> 6;
  const int ln15 = lane & 15, lg = lane >> 4;
  const int row0 = blockIdx.y * 128, col0 = blockIdx.x * 128;
  const int wr = w >> 1, wc = w & 1;

  const int kper = K / gridDim.z;
  const int k0 = blockIdx.z * kper;

  f32x4 acc[4][4] = {};

  const int r0s = tid >> 2,         cc0 = (tid & 3) * 8;
  const int r1s = (256 + tid) >> 2, cc1 = (tid & 3) * 8;

  for (int kt = k0; kt < k0 + kper; kt += 32) {
    async_copy16(A  + (size_t)(row0 + r0s) * K + kt + cc0, (char*)As + ((size_t)w * 64) * 16);
    async_copy16(A  + (size_t)(row0 + r1s) * K + kt + cc1, (char*)As + ((size_t)(256 + w * 64)) * 16);
    async_copy16(Bt + (size_t)(col0 + r0s) * K + kt + cc0, (char*)Bs + ((size_t)w * 64) * 16);
    async_copy16(Bt + (size_t)(col0 + r1s) * K + kt + cc1, (char*)Bs + ((size_t)(256 + w * 64)) * 16);
    __syncthreads();
    short8_t af[4], bfr[4];
#pragma unroll
    for (int m = 0; m < 4; ++m)
      af[m] = *(const short8_t*)(As + (wr*64 + m*16 + ln15) * 32 + lg * 8);
#pragma unroll
    for (int n = 0; n < 4; ++n)
      bfr[n] = *(const short8_t*)(Bs + (wc*64 + n*16 + ln15) * 32 + lg * 8);
#pragma unroll
    for (int m = 0; m < 4; ++m)
#pragma unroll
      for (int n = 0; n < 4; ++n)
        acc[m][n] = mfma16x16x32(af[m], bfr[n], acc[m][n]);
    __syncthreads();
  }

#pragma unroll
  for (int m = 0; m < 4; ++m) {
#pragma unroll
    for (int n = 0; n < 4; ++n) {
#pragma unroll
      for (int r = 0; r < 4; ++r) {
        const int rg = row0 + wr*64 + m*16 + lg*4 + r;
        const int cg = col0 + wc*64 + n*16 + ln15;
        float v = acc[m][n][r];
        if (EPI == 2) {
          v += bias[cg];
          v = 0.5f * v * (1.0f + erff(v * 0.70710678118654752f));
          ((unsigned short*)out)[(size_t)rg * N + cg] = f2bf(v);
        } else {
          ((unsigned short*)out)[((size_t)blockIdx.z * M_ + rg) * (size_t)N + cg] = f2bf(v);
        }
      }
    }
  }
}

// ---------------------------------------------------------------------------
// Flash attention, wave-independent: 1-D grid of 2048 blocks, 64 threads.
// XCD-aware swizzle (T1): hardware round-robins blockIdx%8 across XCDs, so
// block `orig` (on XCD orig&7) takes work item (bh = (orig&7)*4 + (orig>>3)/64,
// qt = (orig>>3)%64). Each XCD then serves 4 bh's -> 1 MB K/V, L2-resident.
// KVBLK=128; P LDS [16][136].
// ---------------------------------------------------------------------------
#define PSTR 136

template<bool MASK>
__device__ __forceinline__ void attn_tile(
    const int g, const int ln15, const int lg, const int rowg0,
    const unsigned short* __restrict__ Kp,
    const unsigned short* __restrict__ Vp,
    const short8_t aq0, const short8_t aq1,
    float* __restrict__ m_run, float* __restrict__ l_run,
    f32x4* __restrict__ o, unsigned short* __restrict__ P) {
  const unsigned short* kt = Kp + (size_t)g * 128 * C_;
  const unsigned short* vt = Vp + g * 128;
  f32x4 s[8];
#pragma unroll
  for (int n = 0; n < 8; ++n) {
    const short8_t b0 = *(const short8_t*)(kt + (size_t)n * 16 * C_);
    const short8_t b1 = *(const short8_t*)(kt + (size_t)n * 16 * C_ + 32);
    f32x4 z = {};
    z = mfma16x16x32(aq0, b0, z);
    s[n] = mfma16x16x32(aq1, b1, z);
  }
  // prefetch V fragments; loads overlap the softmax VALU phase
  short8_t vb[4][4];
#pragma unroll
  for (int c = 0; c < 4; ++c)
#pragma unroll
    for (int n = 0; n < 4; ++n)
      vb[c][n] = *(const short8_t*)(vt + (size_t)n * 16 * T_ + c * 32);

  const float SCL = 0.18033688011116012f;   // (1/8) * log2(e)
  float mx[4];
#pragma unroll
  for (int r = 0; r < 4; ++r) {
    float mr = -1e30f;
#pragma unroll
    for (int n = 0; n < 8; ++n) {
      float v = s[n][r] * SCL;
      if (MASK && (g * 128 + n * 16 + ln15) > (rowg0 + r)) v = -1e30f;
      s[n][r] = v;
      mr = fmaxf(mr, v);
    }
    mx[r] = mr;
  }
#pragma unroll
  for (int d = 1; d < 16; d <<= 1)
#pragma unroll
    for (int r = 0; r < 4; ++r) mx[r] = fmaxf(mx[r], __shfl_xor(mx[r], d, 64));
#pragma unroll
  for (int r = 0; r < 4; ++r) {
    const float mn = fmaxf(m_run[r], mx[r]);
    const float scf = exp2f(m_run[r] - mn);
    m_run[r] = mn;
    float rs = 0.0f;
#pragma unroll
    for (int n = 0; n < 8; ++n) {
      const float pv = exp2f(s[n][r] - mn);
      s[n][r] = pv;
      rs += pv;
    }
#pragma unroll
    for (int d = 1; d < 16; d <<= 1) rs += __shfl_xor(rs, d, 64);
    l_run[r] = l_run[r] * scf + rs;
#pragma unroll
    for (int n = 0; n < 4; ++n) o[n][r] *= scf;
  }
  __syncthreads();   // WAR: prior PV reads done
#pragma unroll
  for (int r = 0; r < 4; ++r)
#pragma unroll
    for (int n = 0; n < 8; ++n)
      P[(lg * 4 + r) * PSTR + n * 16 + ln15] = f2bf(s[n][r]);
  __syncthreads();   // RAW
#pragma unroll
  for (int c = 0; c < 4; ++c) {
    const short8_t pa = *(const short8_t*)(P + ln15 * PSTR + c * 32 + lg * 8);
#pragma unroll
    for (int n = 0; n < 4; ++n)
      o[n] = mfma16x16x32(pa, vb[c][n], o[n]);
  }
}

__global__ __launch_bounds__(64) void attn_k(const unsigned short* __restrict__ Q,
                                             const unsigned short* __restrict__ Kb,
                                             const unsigned short* __restrict__ Vt,
                                             unsigned short* __restrict__ Y) {
  __shared__ __align__(16) unsigned short P[16 * PSTR];
  const int lane = threadIdx.x;
  const int ln15 = lane & 15, lg = lane >> 4;
  // XCD-aware work assignment (see header comment)
  const int orig = blockIdx.x;
  const int xcd = orig & 7;
  const int idx = orig >> 3;          // 0..255 within XCD
  const int bh = xcd * 4 + (idx >> 6);
  const int qt = idx & 63;
  const int b = bh >> 4, h = bh & 15;
  const int q0 = qt * 16;

  short8_t aq0, aq1;
  {
    const unsigned short* qp = Q + ((size_t)(b * T_ + q0 + ln15)) * C_ + h * DH_ + lg * 8;
    aq0 = *(const short8_t*)(qp);
    aq1 = *(const short8_t*)(qp + 32);
  }
  float m_run[4] = { -1e30f, -1e30f, -1e30f, -1e30f };
  float l_run[4] = {};
  f32x4 o[4] = {};
  const int rowg0 = q0 + lg * 4;
  const unsigned short* Kp = Kb + ((size_t)b * T_ + ln15) * C_ + h * DH_ + lg * 8;
  const unsigned short* Vp = Vt + ((size_t)bh * DH_ + ln15) * T_ + lg * 8;

  const int kb_last = qt >> 3;
  for (int kb = 0; kb < kb_last; ++kb)
    attn_tile<false>(kb, ln15, lg, rowg0, Kp, Vp, aq0, aq1, m_run, l_run, o, P);
  attn_tile<true>(kb_last, ln15, lg, rowg0, Kp, Vp, aq0, aq1, m_run, l_run, o, P);

#pragma unroll
  for (int n = 0; n < 4; ++n)
#pragma unroll
    for (int r = 0; r < 4; ++r) {
      const float val = o[n][r] / l_run[r];
      Y[((size_t)(b * T_ + rowg0 + r)) * C_ + h * DH_ + n * 16 + ln15] = f2bf(val);
    }
}

// ---------------------------------------------------------------------------
extern "C" void kernel_launch(void* const* d_in, const int* in_sizes, int n_in,
                              void* d_out, int out_size, void* d_ws, size_t ws_size,
                              hipStream_t stream) {
  const float* x    = (const float*)d_in[0];
  const float* Wq   = (const float*)d_in[1];
  const float* bq   = (const float*)d_in[2];
  const float* Wk   = (const float*)d_in[3];
  const float* bk   = (const float*)d_in[4];
  const float* Wv   = (const float*)d_in[5];
  const float* bv   = (const float*)d_in[6];
  const float* Wo   = (const float*)d_in[7];
  const float* bo   = (const float*)d_in[8];
  const float* ln1s = (const float*)d_in[9];
  const float* ln1b = (const float*)d_in[10];
  const float* ln2s = (const float*)d_in[11];
  const float* ln2b = (const float*)d_in[12];
  const float* W1   = (const float*)d_in[13];
  const float* b1   = (const float*)d_in[14];
  const float* W2   = (const float*)d_in[15];
  const float* b2   = (const float*)d_in[16];
  const float* lnfs = (const float*)d_in[17];
  const float* lnfb = (const float*)d_in[18];

  const size_t MB = (size_t)1 << 20;
  char* ws = (char*)d_ws;
  float*          h      = (float*)(ws + 0);              //  8 MB (B,T,C) f32
  unsigned short* a_bf   = (unsigned short*)(ws + 8*MB);  //  4 MB
  unsigned short* q_bf   = (unsigned short*)(ws + 12*MB); //  4 MB
  unsigned short* k_bf   = (unsigned short*)(ws + 16*MB); //  4 MB
  unsigned short* vt_bf  = (unsigned short*)(ws + 20*MB); //  4 MB (B,H,DH,T)
  unsigned short* y_bf   = (unsigned short*)(ws + 24*MB); //  4 MB
  unsigned short* mid_bf = (unsigned short*)(ws + 28*MB); // 16 MB (M,DFF)
  unsigned short* part   = (unsigned short*)(ws + 44*MB); // 16 MB (4 x 4 MB bf16)
  unsigned short* wt_all = (unsigned short*)(ws + 76*MB); // 192 MB
  float2*         rtab   = (float2*)(ws + 268*MB);        // 256 KB

  // upfront: weights -> bf16^T (per-family launches), rope table, LN1(l=0)
  convert_one<<<8 * 256,  256, 0, stream>>>(Wq, wt_all,            1024, 1024, 256);
  convert_one<<<8 * 256,  256, 0, stream>>>(Wk, wt_all + 1048576,  1024, 1024, 256);
  convert_one<<<8 * 256,  256, 0, stream>>>(Wv, wt_all + 2097152,  1024, 1024, 256);
  convert_one<<<8 * 256,  256, 0, stream>>>(Wo, wt_all + 3145728,  1024, 1024, 256);
  convert_one<<<8 * 1024, 256, 0, stream>>>(W1, wt_all + 4194304,  1024, 4096, 1024);
  convert_one<<<8 * 1024, 256, 0, stream>>>(W2, wt_all + 8388608,  4096, 1024, 1024);
  rope_tab_k<<<128, 256, 0, stream>>>(rtab);
  hipMemcpyAsync(h, x, (size_t)M_ * C_ * sizeof(float), hipMemcpyDeviceToDevice, stream);
  ln_k<<<M_, 256, 0, stream>>>(h, ln1s, ln1b, a_bf);

  for (int l = 0; l < L_; ++l) {
    const unsigned short* wt_l = wt_all + (size_t)l * 12582912;
    // fused QKV GEMM + bias + RoPE(table) + V-transpose (64x128 tile, 768 blocks)
    gemm64<0><<<dim3(24, 32, 1), 256, 0, stream>>>(a_bf, wt_l,
        bq + l*C_, bk + l*C_, bv + l*C_, rtab, q_bf, k_bf, vt_bf, M_, 3*C_, C_);
    // attention: 2048 wave-independent blocks, XCD-swizzled, KVBLK=128
    attn_k<<<2048, 64, 0, stream>>>(q_bf, k_bf, vt_bf, y_bf);
    // output proj, split-K=2 -> bf16 partials (512 blocks)
    gemm64<3><<<dim3(8, 32, 2), 256, 0, stream>>>(y_bf, wt_l + 3145728,
        nullptr, nullptr, nullptr, nullptr, part, nullptr, nullptr, M_, C_, C_);
    // reduce + bo + residual + LN2 -> a_bf
    reduce_ln<2, 0><<<M_, 256, 0, stream>>>(h, bo + l*C_, part,
        ln2s + l*C_, ln2b + l*C_, a_bf);
    // FFN1 + GELU (128^2 tile, 512 blocks)
    gemm128<2><<<dim3(32, 16, 1), 256, 0, stream>>>(a_bf, wt_l + 4194304,
        b1 + l*DFF_, mid_bf, M_, DFF_, C_);
    // FFN2: 128^2 tile, split-K=4 -> bf16 partials (512 blocks, 2/CU)
    gemm128<3><<<dim3(8, 16, 4), 256, 0, stream>>>(mid_bf, wt_l + 8388608,
        nullptr, part, M_, C_, DFF_);
    // reduce + b2 + residual + LN(next or final)
    if (l < L_ - 1) {
      reduce_ln<4, 0><<<M_, 256, 0, stream>>>(h, b2 + l*C_, part,
          ln1s + (l+1)*C_, ln1b + (l+1)*C_, a_bf);
    } else {
      reduce_ln<4, 1><<<M_, 256, 0, stream>>>(h, b2 + l*C_, part,
          lnfs, lnfb, d_out);
    }
  }
}

// Round 17
// 1636.730 us; speedup vs baseline: 1.1622x; 1.0113x over previous
//
#include <hip/hip_runtime.h>
#include <cstdint>
#include <cstddef>

// Problem constants
#define L_   8
#define B_   2
#define T_   1024
#define C_   1024
#define H_   16
#define DH_  64
#define DFF_ 4096
#define M_   2048  // B_*T_

typedef __attribute__((ext_vector_type(4))) float f32x4;
typedef __attribute__((ext_vector_type(8))) short short8_t;
typedef __attribute__((ext_vector_type(8))) __bf16 bf16x8_t;
typedef __attribute__((ext_vector_type(4))) unsigned short ushort4_t;
typedef __attribute__((ext_vector_type(8))) unsigned short ushort8_t;

__device__ __forceinline__ float bf2f(unsigned short u) {
  unsigned int i = ((unsigned int)u) << 16;
  return __builtin_bit_cast(float, i);
}
__device__ __forceinline__ unsigned short f2bf(float f) {
  unsigned int u = __builtin_bit_cast(unsigned int, f);
  u += 0x7fff + ((u >> 16) & 1);   // RNE
  return (unsigned short)(u >> 16);
}
__device__ __forceinline__ f32x4 mfma16x16x32(short8_t a, short8_t b, f32x4 c) {
  return __builtin_amdgcn_mfma_f32_16x16x32_bf16(
      __builtin_bit_cast(bf16x8_t, a), __builtin_bit_cast(bf16x8_t, b), c, 0, 0, 0);
}
__device__ __forceinline__ void async_copy16(const void* g, void* l) {
  __builtin_amdgcn_global_load_lds(
      (const __attribute__((address_space(1))) unsigned int*)g,
      (__attribute__((address_space(3))) unsigned int*)l, 16, 0, 0);
}

// ---------------------------------------------------------------------------
// RoPE cos/sin table: tab[t*32 + j] = (cos, sin)(t * theta^{-2j/64}).
// ---------------------------------------------------------------------------
__global__ __launch_bounds__(256) void rope_tab_k(float2* __restrict__ tab) {
  const int idx = blockIdx.x * 256 + threadIdx.x;   // 0..32767
  const int t = idx >> 5, j = idx & 31;
  const float ang = (float)t * exp2f((float)j * -0.41524101186092029f);
  float sn, cs;
  sincosf(ang, &sn, &cs);
  tab[idx] = make_float2(cs, sn);
}

// ---------------------------------------------------------------------------
// Weight conversion, one matrix family per launch:
// W (R x Cc f32) -> W^T (Cc x R bf16) for all 8 layers. 64x64 tiles,
// rotation swizzle (conflict-free both sides, verified r9).
// ---------------------------------------------------------------------------
__global__ __launch_bounds__(256) void convert_one(
    const float* __restrict__ src0, unsigned short* __restrict__ dst0,
    int R, int Cc, int tilesPerLayer) {
  __shared__ float tile[64 * 64];
  const int layer = blockIdx.x / tilesPerLayer;
  const int t = blockIdx.x - layer * tilesPerLayer;
  const float* src = src0 + (size_t)layer * R * Cc;
  unsigned short* dst = dst0 + (size_t)layer * 12582912;
  const int nTc = Cc >> 6;
  const int tr = t / nTc, tc = t - tr * nTc;
  const int r0 = tr * 64, c0 = tc * 64;
  const int tid = threadIdx.x;
  const int tx = tid & 15, ty = tid >> 4;
#pragma unroll
  for (int i = 0; i < 4; ++i) {
    const int row = ty + 16 * i;
    const float4 v = *(const float4*)(src + (size_t)(r0 + row) * Cc + c0 + tx * 4);
    const int uw = (tx + (row >> 3)) & 15;      // rotation swizzle
    *(float4*)&tile[row * 64 + uw * 4] = v;
  }
  __syncthreads();
#pragma unroll
  for (int pass = 0; pass < 2; ++pass) {
    const int chunk = pass * 256 + tid;
    const int c = chunk >> 3;            // out row (source col)
    const int og = chunk & 7;            // off-group; off = og*8
    const int ur = ((c >> 2) + og) & 15; // matching swizzle
    const int col = ur * 4 + (c & 3);
    ushort8_t val;
#pragma unroll
    for (int j = 0; j < 8; ++j) val[j] = f2bf(tile[(og * 8 + j) * 64 + col]);
    *(ushort8_t*)(dst + (size_t)(c0 + c) * R + r0 + og * 8) = val;
  }
}

// ---------------------------------------------------------------------------
// Plain LayerNorm (layer-0 LN1 only)
// ---------------------------------------------------------------------------
__global__ __launch_bounds__(256) void ln_k(const float* __restrict__ X,
                                            const float* __restrict__ gam,
                                            const float* __restrict__ bet,
                                            unsigned short* __restrict__ out) {
  const int row = blockIdx.x;
  const int tid = threadIdx.x;
  const int lane = tid & 63, w = tid >> 6;
  const float4 v = ((const float4*)(X + (size_t)row * C_))[tid];
  float sum = v.x + v.y + v.z + v.w;
  float sq  = v.x*v.x + v.y*v.y + v.z*v.z + v.w*v.w;
#pragma unroll
  for (int d = 1; d < 64; d <<= 1) {
    sum += __shfl_xor(sum, d, 64);
    sq  += __shfl_xor(sq,  d, 64);
  }
  __shared__ float red[8];
  if (lane == 0) { red[w] = sum; red[4 + w] = sq; }
  __syncthreads();
  sum = red[0] + red[1] + red[2] + red[3];
  sq  = red[4] + red[5] + red[6] + red[7];
  const float mean = sum * (1.0f / C_);
  const float var  = sq * (1.0f / C_) - mean * mean;
  const float inv  = rsqrtf(var + 1e-5f);
  const int col = tid * 4;
  const float xs[4] = { v.x, v.y, v.z, v.w };
  ushort4_t ov;
#pragma unroll
  for (int i = 0; i < 4; ++i)
    ov[i] = f2bf((xs[i]-mean)*inv*gam[col+i] + bet[col+i]);
  *(ushort4_t*)(out + (size_t)row * C_ + col) = ov;
}

// ---------------------------------------------------------------------------
// Fused split-K reduce + bias + residual + LayerNorm. Partials are bf16.
// ---------------------------------------------------------------------------
template<int NS, int FINAL>
__global__ __launch_bounds__(256) void reduce_ln(
    float* __restrict__ h, const float* __restrict__ bias,
    const unsigned short* __restrict__ part,
    const float* __restrict__ gam, const float* __restrict__ bet,
    void* __restrict__ out) {
  const int row = blockIdx.x;
  const int tid = threadIdx.x;
  const int lane = tid & 63, w = tid >> 6;
  const size_t base = (size_t)row * C_;
  float4 v = ((const float4*)(h + base))[tid];
  const float4 b = ((const float4*)bias)[tid];
  v.x += b.x; v.y += b.y; v.z += b.z; v.w += b.w;
#pragma unroll
  for (int z = 0; z < NS; ++z) {
    const ushort4_t p = *(const ushort4_t*)(part + (size_t)z * M_ * C_ + base + tid * 4);
    v.x += bf2f(p[0]); v.y += bf2f(p[1]); v.z += bf2f(p[2]); v.w += bf2f(p[3]);
  }
  if (!FINAL) ((float4*)(h + base))[tid] = v;
  float sum = v.x + v.y + v.z + v.w;
  float sq  = v.x*v.x + v.y*v.y + v.z*v.z + v.w*v.w;
#pragma unroll
  for (int d = 1; d < 64; d <<= 1) {
    sum += __shfl_xor(sum, d, 64);
    sq  += __shfl_xor(sq,  d, 64);
  }
  __shared__ float red[8];
  if (lane == 0) { red[w] = sum; red[4 + w] = sq; }
  __syncthreads();
  sum = red[0] + red[1] + red[2] + red[3];
  sq  = red[4] + red[5] + red[6] + red[7];
  const float mean = sum * (1.0f / C_);
  const float var  = sq * (1.0f / C_) - mean * mean;
  const float inv  = rsqrtf(var + 1e-5f);
  const float4 g  = ((const float4*)gam)[tid];
  const float4 be = ((const float4*)bet)[tid];
  if (FINAL) {
    float4 ov;
    ov.x = (v.x-mean)*inv*g.x + be.x;
    ov.y = (v.y-mean)*inv*g.y + be.y;
    ov.z = (v.z-mean)*inv*g.z + be.z;
    ov.w = (v.w-mean)*inv*g.w + be.w;
    ((float4*)out)[(size_t)row * 256 + tid] = ov;
  } else {
    ushort4_t ov;
    const float xs[4] = { v.x, v.y, v.z, v.w };
    const float gs[4] = { g.x, g.y, g.z, g.w };
    const float bs[4] = { be.x, be.y, be.z, be.w };
#pragma unroll
    for (int i = 0; i < 4; ++i)
      ov[i] = f2bf((xs[i]-mean)*inv*gs[i] + bs[i]);
    *(ushort4_t*)((unsigned short*)out + base + tid * 4) = ov;
  }
}

// ---------------------------------------------------------------------------
// GEMM 64x128 tile, BK=32, 4 waves (2x2) of 32x64. blockIdx.z = K-split.
// EPI 0: QKV (N=3072): +bias, RoPE via table; q,k->bf16 (B,T,C); v->(B,H,DH,T)
// EPI 3: write bf16 partial to out0[z][M][N]
// ---------------------------------------------------------------------------
template<int EPI>
__global__ __launch_bounds__(256) void gemm64(
    const unsigned short* __restrict__ A,
    const unsigned short* __restrict__ Bt,
    const float* __restrict__ bias0,
    const float* __restrict__ bias1,
    const float* __restrict__ bias2,
    const float2* __restrict__ rtab,
    void* __restrict__ out0, void* __restrict__ out1, void* __restrict__ out2,
    int M, int N, int K) {
  __shared__ __align__(16) unsigned short As[64 * 32];
  __shared__ __align__(16) unsigned short Bs[128 * 32];
  const int tid = threadIdx.x;
  const int lane = tid & 63;
  const int w = tid >> 6;
  const int ln15 = lane & 15, lg = lane >> 4;
  const int row0 = blockIdx.y * 64, col0 = blockIdx.x * 128;
  const int wr = w >> 1, wc = w & 1;

  const int kper = K / gridDim.z;
  const int k0 = blockIdx.z * kper;

  f32x4 acc[2][4] = {};

  const int rA  = tid >> 2,          ccA = (tid & 3) * 8;
  const int rB0 = tid >> 2,          ccB = (tid & 3) * 8;
  const int rB1 = (256 + tid) >> 2;

  for (int kt = k0; kt < k0 + kper; kt += 32) {
    async_copy16(A  + (size_t)(row0 + rA)  * K + kt + ccA, (char*)As + ((size_t)w * 64) * 16);
    async_copy16(Bt + (size_t)(col0 + rB0) * K + kt + ccB, (char*)Bs + ((size_t)w * 64) * 16);
    async_copy16(Bt + (size_t)(col0 + rB1) * K + kt + ccB, (char*)Bs + ((size_t)(256 + w * 64)) * 16);
    __syncthreads();
    short8_t af[2], bfr[4];
#pragma unroll
    for (int m = 0; m < 2; ++m)
      af[m] = *(const short8_t*)(As + (wr*32 + m*16 + ln15) * 32 + lg * 8);
#pragma unroll
    for (int n = 0; n < 4; ++n)
      bfr[n] = *(const short8_t*)(Bs + (wc*64 + n*16 + ln15) * 32 + lg * 8);
#pragma unroll
    for (int m = 0; m < 2; ++m)
#pragma unroll
      for (int n = 0; n < 4; ++n)
        acc[m][n] = mfma16x16x32(af[m], bfr[n], acc[m][n]);
    __syncthreads();
  }

#pragma unroll
  for (int m = 0; m < 2; ++m) {
#pragma unroll
    for (int n = 0; n < 4; ++n) {
#pragma unroll
      for (int r = 0; r < 4; ++r) {
        const int rg = row0 + wr*32 + m*16 + lg*4 + r;
        const int cg = col0 + wc*64 + n*16 + ln15;
        float v = acc[m][n][r];
        if (EPI == 0) {
          if (cg < 2048) {
            // q or k: +bias, RoPE from table (pair partner = lane^1)
            v += (cg < 1024) ? bias0[cg] : bias1[cg - 1024];
            const float vp = __shfl_xor(v, 1, 64);
            const int j = (cg & 63) >> 1;
            const float2 cs2 = rtab[((rg & 1023) << 5) + j];
            const float ov = (cg & 1) ? (vp * cs2.y + v * cs2.x)
                                      : (v * cs2.x - vp * cs2.y);
            unsigned short* dstp = (cg < 1024) ? (unsigned short*)out0
                                               : (unsigned short*)out1;
            dstp[(size_t)rg * C_ + (cg & 1023)] = f2bf(ov);
          } else {
            const int ch = cg - 2048;
            v += bias2[ch];
            const int hh = ch >> 6, dh = ch & 63;
            const int bb = rg >> 10, t = rg & 1023;
            // Vt layout: (B,H,DH,T)
            ((unsigned short*)out2)[(((size_t)(bb * H_ + hh) * DH_ + dh) << 10) + t] = f2bf(v);
          }
        } else {
          ((unsigned short*)out0)[((size_t)blockIdx.z * M_ + rg) * (size_t)N + cg] = f2bf(v);
        }
      }
    }
  }
}

// ---------------------------------------------------------------------------
// GEMM 128x128 tile (m97 structure), BK=32, 4 waves of 64x64, optional K-split.
// EPI 2: +bias, exact GELU, write bf16. EPI 3: bf16 partial out[z][M][N].
// ---------------------------------------------------------------------------
template<int EPI>
__global__ __launch_bounds__(256) void gemm128(
    const unsigned short* __restrict__ A,
    const unsigned short* __restrict__ Bt,
    const float* __restrict__ bias,
    void* __restrict__ out,
    int M, int N, int K) {
  __shared__ __align__(16) unsigned short As[128 * 32];
  __shared__ __align__(16) unsigned short Bs[128 * 32];
  const int tid = threadIdx.x;
  const int lane = tid & 63;
  const int w = tid >> 6;
  const int ln15 = lane & 15, lg = lane >> 4;
  const int row0 = blockIdx.y * 128, col0 = blockIdx.x * 128;
  const int wr = w >> 1, wc = w & 1;

  const int kper = K / gridDim.z;
  const int k0 = blockIdx.z * kper;

  f32x4 acc[4][4] = {};

  const int r0s = tid >> 2,         cc0 = (tid & 3) * 8;
  const int r1s = (256 + tid) >> 2, cc1 = (tid & 3) * 8;

  for (int kt = k0; kt < k0 + kper; kt += 32) {
    async_copy16(A  + (size_t)(row0 + r0s) * K + kt + cc0, (char*)As + ((size_t)w * 64) * 16);
    async_copy16(A  + (size_t)(row0 + r1s) * K + kt + cc1, (char*)As + ((size_t)(256 + w * 64)) * 16);
    async_copy16(Bt + (size_t)(col0 + r0s) * K + kt + cc0, (char*)Bs + ((size_t)w * 64) * 16);
    async_copy16(Bt + (size_t)(col0 + r1s) * K + kt + cc1, (char*)Bs + ((size_t)(256 + w * 64)) * 16);
    __syncthreads();
    short8_t af[4], bfr[4];
#pragma unroll
    for (int m = 0; m < 4; ++m)
      af[m] = *(const short8_t*)(As + (wr*64 + m*16 + ln15) * 32 + lg * 8);
#pragma unroll
    for (int n = 0; n < 4; ++n)
      bfr[n] = *(const short8_t*)(Bs + (wc*64 + n*16 + ln15) * 32 + lg * 8);
#pragma unroll
    for (int m = 0; m < 4; ++m)
#pragma unroll
      for (int n = 0; n < 4; ++n)
        acc[m][n] = mfma16x16x32(af[m], bfr[n], acc[m][n]);
    __syncthreads();
  }

#pragma unroll
  for (int m = 0; m < 4; ++m) {
#pragma unroll
    for (int n = 0; n < 4; ++n) {
#pragma unroll
      for (int r = 0; r < 4; ++r) {
        const int rg = row0 + wr*64 + m*16 + lg*4 + r;
        const int cg = col0 + wc*64 + n*16 + ln15;
        float v = acc[m][n][r];
        if (EPI == 2) {
          v += bias[cg];
          v = 0.5f * v * (1.0f + erff(v * 0.70710678118654752f));
          ((unsigned short*)out)[(size_t)rg * N + cg] = f2bf(v);
        } else {
          ((unsigned short*)out)[((size_t)blockIdx.z * M_ + rg) * (size_t)N + cg] = f2bf(v);
        }
      }
    }
  }
}

// ---------------------------------------------------------------------------
// Flash attention, wave-independent: 1-D grid of 2048 blocks, 64 threads.
// XCD-aware swizzle (T1). KVBLK=128; P LDS [16][136].
// Software pipeline: b0-half of next tile's K (bk0[8], 32 VGPR) prefetched
// after current QK^T; its latency hides under softmax+PV. Mask is a
// wave-uniform runtime branch (hot path unmasked).
// ---------------------------------------------------------------------------
#define PSTR 136

__global__ __launch_bounds__(64) void attn_k(const unsigned short* __restrict__ Q,
                                             const unsigned short* __restrict__ Kb,
                                             const unsigned short* __restrict__ Vt,
                                             unsigned short* __restrict__ Y) {
  __shared__ __align__(16) unsigned short P[16 * PSTR];
  const int lane = threadIdx.x;
  const int ln15 = lane & 15, lg = lane >> 4;
  // XCD-aware work assignment: XCD = blockIdx%8 owns 4 bh's (L2-resident K/V)
  const int orig = blockIdx.x;
  const int xcd = orig & 7;
  const int idx = orig >> 3;          // 0..255 within XCD
  const int bh = xcd * 4 + (idx >> 6);
  const int qt = idx & 63;
  const int b = bh >> 4, h = bh & 15;
  const int q0 = qt * 16;

  short8_t aq0, aq1;
  {
    const unsigned short* qp = Q + ((size_t)(b * T_ + q0 + ln15)) * C_ + h * DH_ + lg * 8;
    aq0 = *(const short8_t*)(qp);
    aq1 = *(const short8_t*)(qp + 32);
  }
  float m_run[4] = { -1e30f, -1e30f, -1e30f, -1e30f };
  float l_run[4] = {};
  f32x4 o[4] = {};
  const int rowg0 = q0 + lg * 4;
  const unsigned short* Kp = Kb + ((size_t)b * T_ + ln15) * C_ + h * DH_ + lg * 8;
  const unsigned short* Vp = Vt + ((size_t)bh * DH_ + ln15) * T_ + lg * 8;
  const int kb_last = qt >> 3;
  const float SCL = 0.18033688011116012f;   // (1/8) * log2(e)

  // prologue: prefetch b0-half of tile 0's K
  short8_t bk0[8];
#pragma unroll
  for (int n = 0; n < 8; ++n)
    bk0[n] = *(const short8_t*)(Kp + (size_t)n * 16 * C_);

  for (int g = 0; g <= kb_last; ++g) {
    const bool diag = (g == kb_last);
    const unsigned short* kt = Kp + (size_t)g * 128 * C_;
    const unsigned short* vt = Vp + g * 128;
    // QK^T: b0 from prefetch, b1 loaded here
    f32x4 s[8];
#pragma unroll
    for (int n = 0; n < 8; ++n) {
      const short8_t b1 = *(const short8_t*)(kt + (size_t)n * 16 * C_ + 32);
      f32x4 z = {};
      z = mfma16x16x32(aq0, bk0[n], z);
      s[n] = mfma16x16x32(aq1, b1, z);
    }
    // prefetch next tile's b0-half (latency hides under softmax+PV)
    if (!diag) {
      const unsigned short* ktn = kt + (size_t)128 * C_;
#pragma unroll
      for (int n = 0; n < 8; ++n)
        bk0[n] = *(const short8_t*)(ktn + (size_t)n * 16 * C_);
    }
    // prefetch V fragments; loads overlap the softmax VALU phase
    short8_t vb[4][4];
#pragma unroll
    for (int c = 0; c < 4; ++c)
#pragma unroll
      for (int n = 0; n < 4; ++n)
        vb[c][n] = *(const short8_t*)(vt + (size_t)n * 16 * T_ + c * 32);

    float mx[4];
    if (diag) {
#pragma unroll
      for (int r = 0; r < 4; ++r) {
        float mr = -1e30f;
#pragma unroll
        for (int n = 0; n < 8; ++n) {
          float v = s[n][r] * SCL;
          if ((g * 128 + n * 16 + ln15) > (rowg0 + r)) v = -1e30f;
          s[n][r] = v;
          mr = fmaxf(mr, v);
        }
        mx[r] = mr;
      }
    } else {
#pragma unroll
      for (int r = 0; r < 4; ++r) {
        float mr = -1e30f;
#pragma unroll
        for (int n = 0; n < 8; ++n) {
          const float v = s[n][r] * SCL;
          s[n][r] = v;
          mr = fmaxf(mr, v);
        }
        mx[r] = mr;
      }
    }
#pragma unroll
    for (int d = 1; d < 16; d <<= 1)
#pragma unroll
      for (int r = 0; r < 4; ++r) mx[r] = fmaxf(mx[r], __shfl_xor(mx[r], d, 64));
#pragma unroll
    for (int r = 0; r < 4; ++r) {
      const float mn = fmaxf(m_run[r], mx[r]);
      const float scf = exp2f(m_run[r] - mn);
      m_run[r] = mn;
      float rs = 0.0f;
#pragma unroll
      for (int n = 0; n < 8; ++n) {
        const float pv = exp2f(s[n][r] - mn);
        s[n][r] = pv;
        rs += pv;
      }
#pragma unroll
      for (int d = 1; d < 16; d <<= 1) rs += __shfl_xor(rs, d, 64);
      l_run[r] = l_run[r] * scf + rs;
#pragma unroll
      for (int n = 0; n < 4; ++n) o[n][r] *= scf;
    }
    __syncthreads();   // WAR: prior PV reads done
#pragma unroll
    for (int r = 0; r < 4; ++r)
#pragma unroll
      for (int n = 0; n < 8; ++n)
        P[(lg * 4 + r) * PSTR + n * 16 + ln15] = f2bf(s[n][r]);
    __syncthreads();   // RAW
#pragma unroll
    for (int c = 0; c < 4; ++c) {
      const short8_t pa = *(const short8_t*)(P + ln15 * PSTR + c * 32 + lg * 8);
#pragma unroll
      for (int n = 0; n < 4; ++n)
        o[n] = mfma16x16x32(pa, vb[c][n], o[n]);
    }
  }

#pragma unroll
  for (int n = 0; n < 4; ++n)
#pragma unroll
    for (int r = 0; r < 4; ++r) {
      const float val = o[n][r] / l_run[r];
      Y[((size_t)(b * T_ + rowg0 + r)) * C_ + h * DH_ + n * 16 + ln15] = f2bf(val);
    }
}

// ---------------------------------------------------------------------------
extern "C" void kernel_launch(void* const* d_in, const int* in_sizes, int n_in,
                              void* d_out, int out_size, void* d_ws, size_t ws_size,
                              hipStream_t stream) {
  const float* x    = (const float*)d_in[0];
  const float* Wq   = (const float*)d_in[1];
  const float* bq   = (const float*)d_in[2];
  const float* Wk   = (const float*)d_in[3];
  const float* bk   = (const float*)d_in[4];
  const float* Wv   = (const float*)d_in[5];
  const float* bv   = (const float*)d_in[6];
  const float* Wo   = (const float*)d_in[7];
  const float* bo   = (const float*)d_in[8];
  const float* ln1s = (const float*)d_in[9];
  const float* ln1b = (const float*)d_in[10];
  const float* ln2s = (const float*)d_in[11];
  const float* ln2b = (const float*)d_in[12];
  const float* W1   = (const float*)d_in[13];
  const float* b1   = (const float*)d_in[14];
  const float* W2   = (const float*)d_in[15];
  const float* b2   = (const float*)d_in[16];
  const float* lnfs = (const float*)d_in[17];
  const float* lnfb = (const float*)d_in[18];

  const size_t MB = (size_t)1 << 20;
  char* ws = (char*)d_ws;
  float*          h      = (float*)(ws + 0);              //  8 MB (B,T,C) f32
  unsigned short* a_bf   = (unsigned short*)(ws + 8*MB);  //  4 MB
  unsigned short* q_bf   = (unsigned short*)(ws + 12*MB); //  4 MB
  unsigned short* k_bf   = (unsigned short*)(ws + 16*MB); //  4 MB
  unsigned short* vt_bf  = (unsigned short*)(ws + 20*MB); //  4 MB (B,H,DH,T)
  unsigned short* y_bf   = (unsigned short*)(ws + 24*MB); //  4 MB
  unsigned short* mid_bf = (unsigned short*)(ws + 28*MB); // 16 MB (M,DFF)
  unsigned short* part   = (unsigned short*)(ws + 44*MB); // 16 MB (4 x 4 MB bf16)
  unsigned short* wt_all = (unsigned short*)(ws + 76*MB); // 192 MB
  float2*         rtab   = (float2*)(ws + 268*MB);        // 256 KB

  // upfront: weights -> bf16^T (per-family launches), rope table, LN1(l=0)
  convert_one<<<8 * 256,  256, 0, stream>>>(Wq, wt_all,            1024, 1024, 256);
  convert_one<<<8 * 256,  256, 0, stream>>>(Wk, wt_all + 1048576,  1024, 1024, 256);
  convert_one<<<8 * 256,  256, 0, stream>>>(Wv, wt_all + 2097152,  1024, 1024, 256);
  convert_one<<<8 * 256,  256, 0, stream>>>(Wo, wt_all + 3145728,  1024, 1024, 256);
  convert_one<<<8 * 1024, 256, 0, stream>>>(W1, wt_all + 4194304,  1024, 4096, 1024);
  convert_one<<<8 * 1024, 256, 0, stream>>>(W2, wt_all + 8388608,  4096, 1024, 1024);
  rope_tab_k<<<128, 256, 0, stream>>>(rtab);
  hipMemcpyAsync(h, x, (size_t)M_ * C_ * sizeof(float), hipMemcpyDeviceToDevice, stream);
  ln_k<<<M_, 256, 0, stream>>>(h, ln1s, ln1b, a_bf);

  for (int l = 0; l < L_; ++l) {
    const unsigned short* wt_l = wt_all + (size_t)l * 12582912;
    // fused QKV GEMM + bias + RoPE(table) + V-transpose (64x128 tile, 768 blocks)
    gemm64<0><<<dim3(24, 32, 1), 256, 0, stream>>>(a_bf, wt_l,
        bq + l*C_, bk + l*C_, bv + l*C_, rtab, q_bf, k_bf, vt_bf, M_, 3*C_, C_);
    // attention: 2048 wave-independent blocks, XCD-swizzled, KVBLK=128
    attn_k<<<2048, 64, 0, stream>>>(q_bf, k_bf, vt_bf, y_bf);
    // output proj, split-K=2 -> bf16 partials (512 blocks)
    gemm64<3><<<dim3(8, 32, 2), 256, 0, stream>>>(y_bf, wt_l + 3145728,
        nullptr, nullptr, nullptr, nullptr, part, nullptr, nullptr, M_, C_, C_);
    // reduce + bo + residual + LN2 -> a_bf
    reduce_ln<2, 0><<<M_, 256, 0, stream>>>(h, bo + l*C_, part,
        ln2s + l*C_, ln2b + l*C_, a_bf);
    // FFN1 + GELU (128^2 tile, 512 blocks)
    gemm128<2><<<dim3(32, 16, 1), 256, 0, stream>>>(a_bf, wt_l + 4194304,
        b1 + l*DFF_, mid_bf, M_, DFF_, C_);
    // FFN2: 128^2 tile, split-K=4 -> bf16 partials (512 blocks, 2/CU)
    gemm128<3><<<dim3(8, 16, 4), 256, 0, stream>>>(mid_bf, wt_l + 8388608,
        nullptr, part, M_, C_, DFF_);
    // reduce + b2 + residual + LN(next or final)
    if (l < L_ - 1) {
      reduce_ln<4, 0><<<M_, 256, 0, stream>>>(h, b2 + l*C_, part,
          ln1s + (l+1)*C_, ln1b + (l+1)*C_, a_bf);
    } else {
      reduce_ln<4, 1><<<M_, 256, 0, stream>>>(h, b2 + l*C_, part,
          lnfs, lnfb, d_out);
    }
  }
}